// Round 17
// baseline (213.643 us; speedup 1.0000x reference)
//
#include <hip/hip_runtime.h>

#define NNODES 40000
#define NEDGE  640000
#define NBUCK  625          // buckets per sign, 64 rows each
#define ECAP   1408         // per-bucket capacity (mean 1024, sd ~32)
#define QSZ16  1280000      // ushorts per quarter table (40000*32)
#define QSZU   640000       // uints per quarter table
#define PCHUNK 4096         // edges per partition block
#define PBLKS  313          // ceil(2*NEDGE / PCHUNK)

typedef __attribute__((ext_vector_type(8))) short bfrag;
typedef __attribute__((ext_vector_type(4))) float facc;

union bfu { bfrag v; uint u[4]; };

__device__ inline ushort f2bf(float f) {
    uint u = __float_as_uint(f);
    return (ushort)((u + 0x7FFFu + ((u >> 16) & 1u)) >> 16);
}
__device__ inline float bf2f(ushort h) {
    return __uint_as_float(((uint)h) << 16);
}
__device__ inline float blo(uint u) { return __uint_as_float(u << 16); }
__device__ inline float bhi(uint u) { return __uint_as_float(u & 0xFFFF0000u); }

// ---------------- fused: edge partition (blocks 0..312) + W pack (blocks 313..696) ----

__global__ __launch_bounds__(256) void prep_k(const int* __restrict__ pos_idx,
                                              const float* __restrict__ pos_w,
                                              const int* __restrict__ neg_idx,
                                              const float* __restrict__ neg_w,
                                              int* __restrict__ ecnt,
                                              int2* __restrict__ edges,
                                              const float* __restrict__ Wo,
                                              const float* __restrict__ Wp,
                                              const float* __restrict__ Wn,
                                              const float* __restrict__ Wm,
                                              ushort* __restrict__ wout) {
    __shared__ int lhist[2 * NBUCK];
    __shared__ int lbase[2 * NBUCK];
    __shared__ ushort rows_s[PCHUNK];
    if (blockIdx.x >= PBLKS) {
        // -------- W pack path --------
        int idx = (blockIdx.x - PBLKS) * 256 + threadIdx.x;   // 0..98303
        const float* W;
        ushort* dst;
        int local;
        if (idx < 49152) {
            int m = idx >> 14;
            local = idx & 16383;
            W = (m == 0) ? Wo : (m == 1) ? Wp : Wn;
            dst = wout + m * 16384;
        } else {
            local = idx - 49152;
            W = Wm;
            dst = wout + 49152;
        }
        int j = local & 7, l = (local >> 3) & 63, t = (local >> 9) & 7, ks = local >> 12;
        int k = ks * 32 + (l >> 4) * 8 + j;
        int c = (l & 15) + 16 * t;
        dst[local] = f2bf(W[k * 128 + c]);
        return;
    }
    // -------- partition path --------
    long g0 = (long)blockIdx.x * PCHUNK;
    for (int i = threadIdx.x; i < 2 * NBUCK; i += 256) lhist[i] = 0;
    __syncthreads();
#pragma unroll
    for (int i = 0; i < 16; ++i) {
        long g = g0 + i * 256 + threadIdx.x;
        if (g < 2 * NEDGE) {
            int sign = g >= NEDGE;
            int e = (int)(g - (long)sign * NEDGE);
            int row = sign ? neg_idx[e] : pos_idx[e];
            rows_s[i * 256 + threadIdx.x] = (ushort)row;
            atomicAdd(&lhist[sign * NBUCK + (row >> 6)], 1);
        }
    }
    __syncthreads();
    for (int b = threadIdx.x; b < 2 * NBUCK; b += 256) {
        int c = lhist[b];
        lbase[b] = c ? atomicAdd(&ecnt[b], c) : 0;
        lhist[b] = 0;
    }
    __syncthreads();
#pragma unroll
    for (int i = 0; i < 16; ++i) {
        long g = g0 + i * 256 + threadIdx.x;
        if (g < 2 * NEDGE) {
            int sign = g >= NEDGE;
            int e = (int)(g - (long)sign * NEDGE);
            int row = rows_s[i * 256 + threadIdx.x];
            int col = sign ? neg_idx[NEDGE + e] : pos_idx[NEDGE + e];
            float wv = sign ? neg_w[e] : pos_w[e];
            int b = sign * NBUCK + (row >> 6);
            int off = lbase[b] + atomicAdd(&lhist[b], 1);
            if (off < ECAP)
                edges[(long)b * ECAP + off] =
                    make_int2((int)((uint)col | ((uint)(row & 63) << 16)), __float_as_int(wv));
        }
    }
}

// ---------------- bucket-local counting sort -> compressed CSR ----------------

__global__ __launch_bounds__(256) void bucket_csr_k(const int* __restrict__ ecnt,
                                                    const int2* __restrict__ edges,
                                                    uint* __restrict__ ecomp,
                                                    int2* __restrict__ rp2) {
    __shared__ int2 stage[ECAP];
    __shared__ int hist[64];
    __shared__ int base_[64];
    int b = blockIdx.x;
    int tid = threadIdx.x;
    int cnt = ecnt[b]; if (cnt > ECAP) cnt = ECAP;
    if (tid < 64) hist[tid] = 0;
    __syncthreads();
    long e0 = (long)b * ECAP;
    for (int i = tid; i < cnt; i += 256) {
        int2 e = edges[e0 + i];
        stage[i] = e;
        atomicAdd(&hist[((uint)e.x >> 16) & 63u], 1);
    }
    __syncthreads();
    if (tid < 64) {
        int v = hist[tid];
        int s = v;
#pragma unroll
        for (int off = 1; off < 64; off <<= 1) {
            int t = __shfl_up(s, off);
            if ((tid & 63) >= off) s += t;
        }
        int excl = s - v;
        base_[tid] = excl;
        int sign = b >= NBUCK;
        int r = (b - sign * NBUCK) * 64 + tid;
        rp2[sign * NNODES + r] = make_int2((int)(e0 + excl), (int)(e0 + excl + v));
        hist[tid] = 0;   // reuse as cursor
    }
    __syncthreads();
    for (int i = tid; i < cnt; i += 256) {
        int2 e = stage[i];
        int rl = ((uint)e.x >> 16) & 63u;
        int pos = base_[rl] + atomicAdd(&hist[rl], 1);
        ecomp[e0 + pos] = ((uint)e.x & 0xFFFFu) |
                          ((uint)f2bf(__int_as_float(e.y)) << 16);
    }
}

// ---------------- fused triple MFMA GEMM: x(f32) @ {W_org,W_pos,W_neg} ----------------
// outputs quarter-blocked bf16; fused per-channel stats for org.

__global__ __launch_bounds__(256) void mfma_gemm3_k(const float* __restrict__ x,
                                                    const ushort* __restrict__ B0,
                                                    const ushort* __restrict__ B1,
                                                    const ushort* __restrict__ B2,
                                                    ushort* __restrict__ O0,
                                                    ushort* __restrict__ O1,
                                                    ushort* __restrict__ O2,
                                                    float* __restrict__ sums,
                                                    float* __restrict__ sumsq) {
    __shared__ float cs[128], cq[128];
    int tid = threadIdx.x;
    int lane = tid & 63, wave = tid >> 6;
    if (tid < 128) { cs[tid] = 0.f; cq[tid] = 0.f; }
    __syncthreads();
    long rbase = (long)blockIdx.x * 64 + wave * 16;
    int r = lane & 15, kg = lane >> 4;
    const float* xr = x + (rbase + r) * 128 + kg * 8;
    bfrag a[4];
#pragma unroll
    for (int ks = 0; ks < 4; ++ks) {
        float4 lo = *(const float4*)(xr + ks * 32);
        float4 hi = *(const float4*)(xr + ks * 32 + 4);
        bfu t;
        t.u[0] = (uint)f2bf(lo.x) | ((uint)f2bf(lo.y) << 16);
        t.u[1] = (uint)f2bf(lo.z) | ((uint)f2bf(lo.w) << 16);
        t.u[2] = (uint)f2bf(hi.x) | ((uint)f2bf(hi.y) << 16);
        t.u[3] = (uint)f2bf(hi.z) | ((uint)f2bf(hi.w) << 16);
        a[ks] = t.v;
    }
    const ushort* Bs[3] = {B0, B1, B2};
    ushort* Os[3] = {O0, O1, O2};
    long orow = rbase + kg * 4;
#pragma unroll
    for (int m = 0; m < 3; ++m) {
        const bfrag* Bq = (const bfrag*)Bs[m] + lane;
        facc acc[8];
#pragma unroll
        for (int t = 0; t < 8; ++t) acc[t] = (facc){0.f, 0.f, 0.f, 0.f};
#pragma unroll
        for (int ks = 0; ks < 4; ++ks)
#pragma unroll
            for (int t = 0; t < 8; ++t)
                acc[t] = __builtin_amdgcn_mfma_f32_16x16x32_bf16(a[ks], Bq[(ks * 8 + t) * 64], acc[t], 0, 0, 0);
        ushort* O = Os[m];
#pragma unroll
        for (int t = 0; t < 8; ++t) {
            float s_ = 0.f, q_ = 0.f;
            long qb = (long)(t >> 1) * QSZ16 + (t & 1) * 16 + r;
#pragma unroll
            for (int j = 0; j < 4; ++j) {
                ushort bv = f2bf(acc[t][j]);
                O[qb + (orow + j) * 32] = bv;
                if (m == 0) {
                    float fv = bf2f(bv);
                    s_ += fv;
                    q_ = fmaf(fv, fv, q_);
                }
            }
            if (m == 0) {
                atomicAdd(&cs[16 * t + r], s_);
                atomicAdd(&cq[16 * t + r], q_);
            }
        }
    }
    __syncthreads();
    if (tid < 128) {
        atomicAdd(&sums[tid], cs[tid]);
        atomicAdd(&sumsq[tid], cq[tid]);
    }
}

// ---------------- quarter-blocked SpMM: dual-row predicated interleave ----------
// grp = blockIdx.x & 7 pins each (sign,quarter) group to one XCD (2.56 MB table
// L2-resident). Wave = 32 rows: 16 groups of 4 lanes, each group owns rows
// (r, r+16) walked in ONE branch-free fused loop — per-edge validity folded
// into the weight (invalid -> w=0, index clamped in-range), so 4 independent
// gathers are in flight per group. Coalesced uint4 stores.

template<int PHASE>
__global__ __launch_bounds__(256) void spmmg_k(const int2* __restrict__ rp2,
                                               const uint* __restrict__ ec,
                                               const uint* __restrict__ p_in,
                                               const uint* __restrict__ n_in,
                                               const uint* __restrict__ p_prev,
                                               const uint* __restrict__ n_prev,
                                               uint* __restrict__ p_out,
                                               uint* __restrict__ n_out) {
    int grp = blockIdx.x & 7;
    int rg  = blockIdx.x >> 3;          // 0..312
    int sign = grp >> 2, q = grp & 3;
    int tid = threadIdx.x;
    int w = tid >> 6, lane = tid & 63;
    int u = lane & 3;                   // uint4 index (8 bf16 channels)
    int rl = lane >> 2;                 // 0..15
    const uint4* in  = (const uint4*)((sign ? n_in : p_in) + q * QSZU);
    uint4* out = (uint4*)((sign ? n_out : p_out) + q * QSZU);
    int rA = rg * 128 + w * 32 + rl;    // 0..40063 (last block partially OOB)
    int rB = rA + 16;
    int2 seA = (rA < NNODES) ? rp2[sign * NNODES + rA] : make_int2(0, 0);
    int2 seB = (rB < NNODES) ? rp2[sign * NNODES + rB] : make_int2(0, 0);
    float a0 = 0.f, a1 = 0.f, a2 = 0.f, a3 = 0.f;
    float a4 = 0.f, a5 = 0.f, a6 = 0.f, a7 = 0.f;
    float c0 = 0.f, c1 = 0.f, c2 = 0.f, c3 = 0.f;
    float c4 = 0.f, c5 = 0.f, c6 = 0.f, c7 = 0.f;
    int eA = seA.x, eAn = seA.y, sA = seA.x;
    int eB = seB.x, eBn = seB.y, sB = seB.x;
    while (eA < eAn || eB < eBn) {
        int iA0 = (eA < eAn)     ? eA     : sA;
        int iA1 = (eA + 1 < eAn) ? eA + 1 : sA;
        int iB0 = (eB < eBn)     ? eB     : sB;
        int iB1 = (eB + 1 < eBn) ? eB + 1 : sB;
        uint wdA0 = ec[iA0], wdA1 = ec[iA1];
        uint wdB0 = ec[iB0], wdB1 = ec[iB1];
        uint4 gA0 = in[(wdA0 & 0xFFFFu) * 4 + u];
        uint4 gA1 = in[(wdA1 & 0xFFFFu) * 4 + u];
        uint4 gB0 = in[(wdB0 & 0xFFFFu) * 4 + u];
        uint4 gB1 = in[(wdB1 & 0xFFFFu) * 4 + u];
        float wA0 = (eA < eAn)     ? bhi(wdA0) : 0.f;
        float wA1 = (eA + 1 < eAn) ? bhi(wdA1) : 0.f;
        float wB0 = (eB < eBn)     ? bhi(wdB0) : 0.f;
        float wB1 = (eB + 1 < eBn) ? bhi(wdB1) : 0.f;
        a0 = fmaf(wA0, blo(gA0.x), a0); a1 = fmaf(wA0, bhi(gA0.x), a1);
        a2 = fmaf(wA0, blo(gA0.y), a2); a3 = fmaf(wA0, bhi(gA0.y), a3);
        a4 = fmaf(wA0, blo(gA0.z), a4); a5 = fmaf(wA0, bhi(gA0.z), a5);
        a6 = fmaf(wA0, blo(gA0.w), a6); a7 = fmaf(wA0, bhi(gA0.w), a7);
        c0 = fmaf(wB0, blo(gB0.x), c0); c1 = fmaf(wB0, bhi(gB0.x), c1);
        c2 = fmaf(wB0, blo(gB0.y), c2); c3 = fmaf(wB0, bhi(gB0.y), c3);
        c4 = fmaf(wB0, blo(gB0.z), c4); c5 = fmaf(wB0, bhi(gB0.z), c5);
        c6 = fmaf(wB0, blo(gB0.w), c6); c7 = fmaf(wB0, bhi(gB0.w), c7);
        a0 = fmaf(wA1, blo(gA1.x), a0); a1 = fmaf(wA1, bhi(gA1.x), a1);
        a2 = fmaf(wA1, blo(gA1.y), a2); a3 = fmaf(wA1, bhi(gA1.y), a3);
        a4 = fmaf(wA1, blo(gA1.z), a4); a5 = fmaf(wA1, bhi(gA1.z), a5);
        a6 = fmaf(wA1, blo(gA1.w), a6); a7 = fmaf(wA1, bhi(gA1.w), a7);
        c0 = fmaf(wB1, blo(gB1.x), c0); c1 = fmaf(wB1, bhi(gB1.x), c1);
        c2 = fmaf(wB1, blo(gB1.y), c2); c3 = fmaf(wB1, bhi(gB1.y), c3);
        c4 = fmaf(wB1, blo(gB1.z), c4); c5 = fmaf(wB1, bhi(gB1.z), c5);
        c6 = fmaf(wB1, blo(gB1.w), c6); c7 = fmaf(wB1, bhi(gB1.w), c7);
        eA += 2; eB += 2;
    }
    if (PHASE == 1) {
        if (rA < NNODES) {
            uint4 res;
            res.x = (uint)f2bf(2.f * a0) | ((uint)f2bf(2.f * a1) << 16);
            res.y = (uint)f2bf(2.f * a2) | ((uint)f2bf(2.f * a3) << 16);
            res.z = (uint)f2bf(2.f * a4) | ((uint)f2bf(2.f * a5) << 16);
            res.w = (uint)f2bf(2.f * a6) | ((uint)f2bf(2.f * a7) << 16);
            out[rA * 4 + u] = res;
        }
        if (rB < NNODES) {
            uint4 res;
            res.x = (uint)f2bf(2.f * c0) | ((uint)f2bf(2.f * c1) << 16);
            res.y = (uint)f2bf(2.f * c2) | ((uint)f2bf(2.f * c3) << 16);
            res.z = (uint)f2bf(2.f * c4) | ((uint)f2bf(2.f * c5) << 16);
            res.w = (uint)f2bf(2.f * c6) | ((uint)f2bf(2.f * c7) << 16);
            out[rB * 4 + u] = res;
        }
    } else {
        const uint4* prev = (const uint4*)((sign ? n_prev : p_prev) + q * QSZU);
        if (rA < NNODES) {
            uint4 pu = prev[rA * 4 + u];
            float r0 = fmaf(1.875f, a0, -1.6875f * blo(pu.x));
            float r1 = fmaf(1.875f, a1, -1.6875f * bhi(pu.x));
            float r2 = fmaf(1.875f, a2, -1.6875f * blo(pu.y));
            float r3 = fmaf(1.875f, a3, -1.6875f * bhi(pu.y));
            float r4 = fmaf(1.875f, a4, -1.6875f * blo(pu.z));
            float r5 = fmaf(1.875f, a5, -1.6875f * bhi(pu.z));
            float r6 = fmaf(1.875f, a6, -1.6875f * blo(pu.w));
            float r7 = fmaf(1.875f, a7, -1.6875f * bhi(pu.w));
            uint4 res;
            res.x = (uint)f2bf(r0) | ((uint)f2bf(r1) << 16);
            res.y = (uint)f2bf(r2) | ((uint)f2bf(r3) << 16);
            res.z = (uint)f2bf(r4) | ((uint)f2bf(r5) << 16);
            res.w = (uint)f2bf(r6) | ((uint)f2bf(r7) << 16);
            out[rA * 4 + u] = res;
        }
        if (rB < NNODES) {
            uint4 pu = prev[rB * 4 + u];
            float r0 = fmaf(1.875f, c0, -1.6875f * blo(pu.x));
            float r1 = fmaf(1.875f, c1, -1.6875f * bhi(pu.x));
            float r2 = fmaf(1.875f, c2, -1.6875f * blo(pu.y));
            float r3 = fmaf(1.875f, c3, -1.6875f * bhi(pu.y));
            float r4 = fmaf(1.875f, c4, -1.6875f * blo(pu.z));
            float r5 = fmaf(1.875f, c5, -1.6875f * bhi(pu.z));
            float r6 = fmaf(1.875f, c6, -1.6875f * blo(pu.w));
            float r7 = fmaf(1.875f, c7, -1.6875f * bhi(pu.w));
            uint4 res;
            res.x = (uint)f2bf(r0) | ((uint)f2bf(r1) << 16);
            res.y = (uint)f2bf(r2) | ((uint)f2bf(r3) << 16);
            res.z = (uint)f2bf(r4) | ((uint)f2bf(r5) << 16);
            res.w = (uint)f2bf(r6) | ((uint)f2bf(r7) << 16);
            out[rB * 4 + u] = res;
        }
    }
}

// ---------------- batch stats for pos & neg (quarter-blocked bf16 input) ----------------

__global__ __launch_bounds__(256) void stats2_k(const ushort* __restrict__ pos,
                                                const ushort* __restrict__ neg,
                                                float* __restrict__ sums,
                                                float* __restrict__ sumsq) {
    int b = blockIdx.x;            // 626 blocks
    int sign = b >= 313;
    int blk = b - sign * 313;
    const ushort* buf = sign ? neg : pos;
    int c = threadIdx.x & 127, half = threadIdx.x >> 7;
    int qq = c >> 5, cc = c & 31;
    const ushort* base = buf + (long)qq * QSZ16 + cc;
    int r0 = blk * 128;
    int rend = r0 + 128; if (rend > NNODES) rend = NNODES;
    float s = 0.f, s2 = 0.f;
    for (int r = r0 + half; r < rend; r += 2) {
        float v = bf2f(base[r * 32]);
        s += v;
        s2 = fmaf(v, v, s2);
    }
    __shared__ float sh[256], sh2[256];
    sh[threadIdx.x] = s; sh2[threadIdx.x] = s2;
    __syncthreads();
    if (threadIdx.x < 128) {
        int sb = 128 + sign * 128;
        atomicAdd(&sums[sb + c],  sh[c]  + sh[c + 128]);
        atomicAdd(&sumsq[sb + c], sh2[c] + sh2[c + 128]);
    }
}

// ---------------- final MFMA GEMM K=384: BN-finalize + BN+PReLU+concat + row-norm ----

__global__ __launch_bounds__(256) void mfma_gemm_mlp_k(const ushort* __restrict__ org,
                                                       const ushort* __restrict__ pos,
                                                       const ushort* __restrict__ neg,
                                                       const float* __restrict__ sums,
                                                       const float* __restrict__ sumsq,
                                                       const float* __restrict__ g0,
                                                       const float* __restrict__ be0,
                                                       const float* __restrict__ g1,
                                                       const float* __restrict__ be1,
                                                       const float* __restrict__ g2,
                                                       const float* __restrict__ be2,
                                                       const float* __restrict__ prelu_w,
                                                       const ushort* __restrict__ Bp,
                                                       float* __restrict__ Out) {
    __shared__ __align__(16) float bnl[768];
    int tid = threadIdx.x;
    for (int i = tid; i < 384; i += 256) {
        int s = i >> 7, c = i & 127;
        float mean = sums[i] * (1.f / NNODES);
        float var  = sumsq[i] * (1.f / NNODES) - mean * mean;
        const float* g = (s == 0) ? g0 : (s == 1) ? g1 : g2;
        const float* b = (s == 0) ? be0 : (s == 1) ? be1 : be2;
        float sc = g[c] * rsqrtf(var + 1e-5f);
        bnl[s * 256 + c]       = sc;
        bnl[s * 256 + 128 + c] = b[c] - mean * sc;
    }
    __syncthreads();
    int lane = tid & 63, wave = tid >> 6;
    long rbase = (long)blockIdx.x * 64 + wave * 16;
    int r = lane & 15, kg = lane >> 4;
    float pw = prelu_w[0];
    facc acc[8];
#pragma unroll
    for (int t = 0; t < 8; ++t) acc[t] = (facc){0.f, 0.f, 0.f, 0.f};
    const bfrag* Bq = (const bfrag*)Bp + lane;
#pragma unroll
    for (int ks = 0; ks < 12; ++ks) {
        int c = ks * 32 + kg * 8;          // concat column of first elem
        int s = c >> 7;
        int off = c & 127;
        const ushort* src = (s == 0) ? org : (s == 1) ? pos : neg;
        const uint* srcu = (const uint*)src;
        uint4 u = *(const uint4*)(srcu + (long)(off >> 5) * QSZU + (rbase + r) * 16 + ((off & 31) >> 1));
        float4 sc_lo = *(const float4*)(bnl + s * 256 + off);
        float4 sc_hi = *(const float4*)(bnl + s * 256 + off + 4);
        float4 sh_lo = *(const float4*)(bnl + s * 256 + 128 + off);
        float4 sh_hi = *(const float4*)(bnl + s * 256 + 128 + off + 4);
        uint uu[4] = {u.x, u.y, u.z, u.w};
        float scv[8] = {sc_lo.x, sc_lo.y, sc_lo.z, sc_lo.w, sc_hi.x, sc_hi.y, sc_hi.z, sc_hi.w};
        float shv[8] = {sh_lo.x, sh_lo.y, sh_lo.z, sh_lo.w, sh_hi.x, sh_hi.y, sh_hi.z, sh_hi.w};
        bfu av;
#pragma unroll
        for (int k = 0; k < 4; ++k) {
            float vx = __uint_as_float(uu[k] << 16);
            float vy = __uint_as_float(uu[k] & 0xFFFF0000u);
            float ox = fmaf(vx, scv[2 * k],     shv[2 * k]);     ox = (ox >= 0.f) ? ox : pw * ox;
            float oy = fmaf(vy, scv[2 * k + 1], shv[2 * k + 1]); oy = (oy >= 0.f) ? oy : pw * oy;
            av.u[k] = (uint)f2bf(ox) | ((uint)f2bf(oy) << 16);
        }
#pragma unroll
        for (int t = 0; t < 8; ++t)
            acc[t] = __builtin_amdgcn_mfma_f32_16x16x32_bf16(av.v, Bq[(ks * 8 + t) * 64], acc[t], 0, 0, 0);
    }
    long orow = rbase + kg * 4;
#pragma unroll
    for (int j = 0; j < 4; ++j) {
        float ss = 0.f;
#pragma unroll
        for (int t = 0; t < 8; ++t) ss = fmaf(acc[t][j], acc[t][j], ss);
        ss += __shfl_xor(ss, 1);
        ss += __shfl_xor(ss, 2);
        ss += __shfl_xor(ss, 4);
        ss += __shfl_xor(ss, 8);
        float inv = 1.f / fmaxf(sqrtf(ss), 1e-12f);
#pragma unroll
        for (int t = 0; t < 8; ++t)
            Out[(orow + j) * 128 + 16 * t + r] = acc[t][j] * inv;
    }
}

// ---------------- launch ----------------

extern "C" void kernel_launch(void* const* d_in, const int* in_sizes, int n_in,
                              void* d_out, int out_size, void* d_ws, size_t ws_size,
                              hipStream_t stream) {
    const float* x       = (const float*)d_in[0];
    const int*   pos_idx = (const int*)d_in[1];
    const float* pos_w   = (const float*)d_in[2];
    const int*   neg_idx = (const int*)d_in[3];
    const float* neg_w   = (const float*)d_in[4];
    const float* W_org   = (const float*)d_in[5];
    const float* W_pos   = (const float*)d_in[6];
    const float* W_neg   = (const float*)d_in[7];
    const float* g_org   = (const float*)d_in[8];
    const float* b_org   = (const float*)d_in[9];
    const float* g_pos   = (const float*)d_in[10];
    const float* b_pos   = (const float*)d_in[11];
    const float* g_neg   = (const float*)d_in[12];
    const float* b_neg   = (const float*)d_in[13];
    const float* prelu_w = (const float*)d_in[14];
    const float* W_mlp   = (const float*)d_in[15];
    float* out = (float*)d_out;

    char* ws = (char*)d_ws;
    const size_t FB = (size_t)NNODES * 128 * 2;        // 10,240,000 B per feature buffer
    ushort* org0b = (ushort*)(ws);
    ushort* p0b   = (ushort*)(ws + FB);
    ushort* n0b   = (ushort*)(ws + 2 * FB);
    int2* edges   = (int2*)(ws + 3 * FB);              // staging, 14,080,000 B
    uint* ecomp   = (uint*)(ws + 3 * FB + 14080000);   // compressed, 7,040,000 B
    char* small   = ws + 3 * FB + 14080000 + 7040000;
    int* ecnt     = (int*)small;                       // 5000 -> pad 5120
    float* sums   = (float*)(small + 5120);            // 1536
    float* sumsq  = (float*)(small + 5120 + 1536);     // 1536 (memset 0..8192)
    int2* rp2     = (int2*)(small + 8192);             // 640,000
    ushort* Wb    = (ushort*)(small + 8192 + 640000);  // 196,608 B
    uint* t1_pos  = (uint*)d_out;                      // blocked bf16 scratch halves of d_out
    uint* t1_neg  = (uint*)d_out + 4 * QSZU;

    hipMemsetAsync(small, 0, 8192, stream);

    prep_k<<<PBLKS + 384, 256, 0, stream>>>(pos_idx, pos_w, neg_idx, neg_w, ecnt, edges,
                                            W_org, W_pos, W_neg, W_mlp, Wb);
    bucket_csr_k<<<2 * NBUCK, 256, 0, stream>>>(ecnt, edges, ecomp, rp2);

    mfma_gemm3_k<<<625, 256, 0, stream>>>(x, Wb, Wb + 16384, Wb + 32768,
                                          org0b, p0b, n0b, sums, sumsq);

    // Jacobi (a=b=1, K=3): x1 = 2*A@x0 ; x2 = 1.875*A@x1 - 1.6875*x0
    spmmg_k<1><<<2504, 256, 0, stream>>>(rp2, ecomp,
        (const uint*)p0b, (const uint*)n0b, nullptr, nullptr, t1_pos, t1_neg);
    spmmg_k<2><<<2504, 256, 0, stream>>>(rp2, ecomp,
        t1_pos, t1_neg, (const uint*)p0b, (const uint*)n0b, (uint*)p0b, (uint*)n0b);

    stats2_k<<<626, 256, 0, stream>>>(p0b, n0b, sums, sumsq);
    mfma_gemm_mlp_k<<<625, 256, 0, stream>>>(org0b, p0b, n0b, sums, sumsq,
                                             g_org, b_org, g_pos, b_pos, g_neg, b_neg,
                                             prelu_w, Wb + 49152, out);

    (void)in_sizes; (void)n_in; (void)out_size; (void)ws_size;
}

// Round 18
// 208.345 us; speedup vs baseline: 1.0254x; 1.0254x over previous
//
#include <hip/hip_runtime.h>

#define NNODES 40000
#define NEDGE  640000
#define NBUCK  625          // buckets per sign, 64 rows each
#define ECAP   1408         // per-bucket capacity (mean 1024, sd ~32)
#define QSZ16  1280000      // ushorts per quarter table (40000*32)
#define QSZU   640000       // uints per quarter table
#define PCHUNK 4096         // edges per partition block
#define PBLKS  313          // ceil(2*NEDGE / PCHUNK)

typedef __attribute__((ext_vector_type(8))) short bfrag;
typedef __attribute__((ext_vector_type(4))) float facc;

union bfu { bfrag v; uint u[4]; };

__device__ inline ushort f2bf(float f) {
    uint u = __float_as_uint(f);
    return (ushort)((u + 0x7FFFu + ((u >> 16) & 1u)) >> 16);
}
__device__ inline float bf2f(ushort h) {
    return __uint_as_float(((uint)h) << 16);
}
__device__ inline float blo(uint u) { return __uint_as_float(u << 16); }
__device__ inline float bhi(uint u) { return __uint_as_float(u & 0xFFFF0000u); }

// ---------------- fused: edge partition (blocks 0..312) + W pack (blocks 313..696) ----

__global__ __launch_bounds__(256) void prep_k(const int* __restrict__ pos_idx,
                                              const float* __restrict__ pos_w,
                                              const int* __restrict__ neg_idx,
                                              const float* __restrict__ neg_w,
                                              int* __restrict__ ecnt,
                                              int2* __restrict__ edges,
                                              const float* __restrict__ Wo,
                                              const float* __restrict__ Wp,
                                              const float* __restrict__ Wn,
                                              const float* __restrict__ Wm,
                                              ushort* __restrict__ wout) {
    __shared__ int lhist[2 * NBUCK];
    __shared__ int lbase[2 * NBUCK];
    __shared__ ushort rows_s[PCHUNK];
    if (blockIdx.x >= PBLKS) {
        // -------- W pack path --------
        int idx = (blockIdx.x - PBLKS) * 256 + threadIdx.x;   // 0..98303
        const float* W;
        ushort* dst;
        int local;
        if (idx < 49152) {
            int m = idx >> 14;
            local = idx & 16383;
            W = (m == 0) ? Wo : (m == 1) ? Wp : Wn;
            dst = wout + m * 16384;
        } else {
            local = idx - 49152;
            W = Wm;
            dst = wout + 49152;
        }
        int j = local & 7, l = (local >> 3) & 63, t = (local >> 9) & 7, ks = local >> 12;
        int k = ks * 32 + (l >> 4) * 8 + j;
        int c = (l & 15) + 16 * t;
        dst[local] = f2bf(W[k * 128 + c]);
        return;
    }
    // -------- partition path --------
    long g0 = (long)blockIdx.x * PCHUNK;
    for (int i = threadIdx.x; i < 2 * NBUCK; i += 256) lhist[i] = 0;
    __syncthreads();
#pragma unroll
    for (int i = 0; i < 16; ++i) {
        long g = g0 + i * 256 + threadIdx.x;
        if (g < 2 * NEDGE) {
            int sign = g >= NEDGE;
            int e = (int)(g - (long)sign * NEDGE);
            int row = sign ? neg_idx[e] : pos_idx[e];
            rows_s[i * 256 + threadIdx.x] = (ushort)row;
            atomicAdd(&lhist[sign * NBUCK + (row >> 6)], 1);
        }
    }
    __syncthreads();
    for (int b = threadIdx.x; b < 2 * NBUCK; b += 256) {
        int c = lhist[b];
        lbase[b] = c ? atomicAdd(&ecnt[b], c) : 0;
        lhist[b] = 0;
    }
    __syncthreads();
#pragma unroll
    for (int i = 0; i < 16; ++i) {
        long g = g0 + i * 256 + threadIdx.x;
        if (g < 2 * NEDGE) {
            int sign = g >= NEDGE;
            int e = (int)(g - (long)sign * NEDGE);
            int row = rows_s[i * 256 + threadIdx.x];
            int col = sign ? neg_idx[NEDGE + e] : pos_idx[NEDGE + e];
            float wv = sign ? neg_w[e] : pos_w[e];
            int b = sign * NBUCK + (row >> 6);
            int off = lbase[b] + atomicAdd(&lhist[b], 1);
            if (off < ECAP)
                edges[(long)b * ECAP + off] =
                    make_int2((int)((uint)col | ((uint)(row & 63) << 16)), __float_as_int(wv));
        }
    }
}

// ---------------- fused mid stage: bucket CSR (blocks 0..1249) + gemm3 (1250..1874) ----
// Both depend only on prep_k and are mutually independent: one dispatch runs
// them concurrently (LDS-bound sort overlaps MFMA-bound GEMM), wall ~= max.

__global__ __launch_bounds__(256) void mid_k(const int* __restrict__ ecnt,
                                             const int2* __restrict__ edges,
                                             uint* __restrict__ ecomp,
                                             int2* __restrict__ rp2,
                                             const float* __restrict__ x,
                                             const ushort* __restrict__ B0,
                                             const ushort* __restrict__ B1,
                                             const ushort* __restrict__ B2,
                                             ushort* __restrict__ O0,
                                             ushort* __restrict__ O1,
                                             ushort* __restrict__ O2,
                                             float* __restrict__ sums,
                                             float* __restrict__ sumsq) {
    int tid = threadIdx.x;
    if (blockIdx.x < 2 * NBUCK) {
        // ---------------- bucket-local counting sort -> compressed CSR ----------------
        __shared__ int2 stage[ECAP];
        __shared__ int hist[64];
        __shared__ int base_[64];
        int b = blockIdx.x;
        int cnt = ecnt[b]; if (cnt > ECAP) cnt = ECAP;
        if (tid < 64) hist[tid] = 0;
        __syncthreads();
        long e0 = (long)b * ECAP;
        for (int i = tid; i < cnt; i += 256) {
            int2 e = edges[e0 + i];
            stage[i] = e;
            atomicAdd(&hist[((uint)e.x >> 16) & 63u], 1);
        }
        __syncthreads();
        if (tid < 64) {
            int v = hist[tid];
            int s = v;
#pragma unroll
            for (int off = 1; off < 64; off <<= 1) {
                int t = __shfl_up(s, off);
                if ((tid & 63) >= off) s += t;
            }
            int excl = s - v;
            base_[tid] = excl;
            int sign = b >= NBUCK;
            int r = (b - sign * NBUCK) * 64 + tid;
            rp2[sign * NNODES + r] = make_int2((int)(e0 + excl), (int)(e0 + excl + v));
            hist[tid] = 0;   // reuse as cursor
        }
        __syncthreads();
        for (int i = tid; i < cnt; i += 256) {
            int2 e = stage[i];
            int rl = ((uint)e.x >> 16) & 63u;
            int pos = base_[rl] + atomicAdd(&hist[rl], 1);
            ecomp[e0 + pos] = ((uint)e.x & 0xFFFFu) |
                              ((uint)f2bf(__int_as_float(e.y)) << 16);
        }
        return;
    }
    // ---------------- triple MFMA GEMM: x(f32) @ {W_org,W_pos,W_neg} ----------------
    __shared__ float cs[128], cq[128];
    int lane = tid & 63, wave = tid >> 6;
    if (tid < 128) { cs[tid] = 0.f; cq[tid] = 0.f; }
    __syncthreads();
    long rbase = (long)(blockIdx.x - 2 * NBUCK) * 64 + wave * 16;
    int r = lane & 15, kg = lane >> 4;
    const float* xr = x + (rbase + r) * 128 + kg * 8;
    bfrag a[4];
#pragma unroll
    for (int ks = 0; ks < 4; ++ks) {
        float4 lo = *(const float4*)(xr + ks * 32);
        float4 hi = *(const float4*)(xr + ks * 32 + 4);
        bfu t;
        t.u[0] = (uint)f2bf(lo.x) | ((uint)f2bf(lo.y) << 16);
        t.u[1] = (uint)f2bf(lo.z) | ((uint)f2bf(lo.w) << 16);
        t.u[2] = (uint)f2bf(hi.x) | ((uint)f2bf(hi.y) << 16);
        t.u[3] = (uint)f2bf(hi.z) | ((uint)f2bf(hi.w) << 16);
        a[ks] = t.v;
    }
    const ushort* Bs[3] = {B0, B1, B2};
    ushort* Os[3] = {O0, O1, O2};
    long orow = rbase + kg * 4;
#pragma unroll
    for (int m = 0; m < 3; ++m) {
        const bfrag* Bq = (const bfrag*)Bs[m] + lane;
        facc acc[8];
#pragma unroll
        for (int t = 0; t < 8; ++t) acc[t] = (facc){0.f, 0.f, 0.f, 0.f};
#pragma unroll
        for (int ks = 0; ks < 4; ++ks)
#pragma unroll
            for (int t = 0; t < 8; ++t)
                acc[t] = __builtin_amdgcn_mfma_f32_16x16x32_bf16(a[ks], Bq[(ks * 8 + t) * 64], acc[t], 0, 0, 0);
        ushort* O = Os[m];
#pragma unroll
        for (int t = 0; t < 8; ++t) {
            float s_ = 0.f, q_ = 0.f;
            long qb = (long)(t >> 1) * QSZ16 + (t & 1) * 16 + r;
#pragma unroll
            for (int j = 0; j < 4; ++j) {
                ushort bv = f2bf(acc[t][j]);
                O[qb + (orow + j) * 32] = bv;
                if (m == 0) {
                    float fv = bf2f(bv);
                    s_ += fv;
                    q_ = fmaf(fv, fv, q_);
                }
            }
            if (m == 0) {
                atomicAdd(&cs[16 * t + r], s_);
                atomicAdd(&cq[16 * t + r], q_);
            }
        }
    }
    __syncthreads();
    if (tid < 128) {
        atomicAdd(&sums[tid], cs[tid]);
        atomicAdd(&sumsq[tid], cq[tid]);
    }
}

// ---------------- quarter-blocked SpMM: 16 rows/wave x 4 lanes, uint4 gathers ----------
// (byte-identical to the round-14 form that measured 45.4 us/dispatch)

template<int PHASE>
__global__ __launch_bounds__(256) void spmmg_k(const int2* __restrict__ rp2,
                                               const uint* __restrict__ ec,
                                               const uint* __restrict__ p_in,
                                               const uint* __restrict__ n_in,
                                               const uint* __restrict__ p_prev,
                                               const uint* __restrict__ n_prev,
                                               uint* __restrict__ p_out,
                                               uint* __restrict__ n_out) {
    int grp = blockIdx.x & 7;
    int rg  = blockIdx.x >> 3;          // 0..624
    int sign = grp >> 2, q = grp & 3;
    int tid = threadIdx.x;
    int w = tid >> 6, lane = tid & 63;
    int u = lane & 3;                   // uint4 index (8 bf16 channels)
    int rl = lane >> 2;                 // row within wave (0..15)
    const uint4* in  = (const uint4*)((sign ? n_in : p_in) + q * QSZU);
    uint4* out = (uint4*)((sign ? n_out : p_out) + q * QSZU);
    int r = rg * 64 + w * 16 + rl;
    int2 se = rp2[sign * NNODES + r];
    float a0 = 0.f, a1 = 0.f, a2 = 0.f, a3 = 0.f;
    float a4 = 0.f, a5 = 0.f, a6 = 0.f, a7 = 0.f;
    float b0 = 0.f, b1 = 0.f, b2 = 0.f, b3 = 0.f;
    float b4 = 0.f, b5 = 0.f, b6 = 0.f, b7 = 0.f;
    int e = se.x, e1 = se.y;
    for (; e + 2 <= e1; e += 2) {
        uint ea = ec[e], eb = ec[e + 1];
        uint4 ga = in[(ea & 0xFFFFu) * 4 + u];
        uint4 gb = in[(eb & 0xFFFFu) * 4 + u];
        float wa = bhi(ea), wb = bhi(eb);
        a0 = fmaf(wa, blo(ga.x), a0); a1 = fmaf(wa, bhi(ga.x), a1);
        a2 = fmaf(wa, blo(ga.y), a2); a3 = fmaf(wa, bhi(ga.y), a3);
        a4 = fmaf(wa, blo(ga.z), a4); a5 = fmaf(wa, bhi(ga.z), a5);
        a6 = fmaf(wa, blo(ga.w), a6); a7 = fmaf(wa, bhi(ga.w), a7);
        b0 = fmaf(wb, blo(gb.x), b0); b1 = fmaf(wb, bhi(gb.x), b1);
        b2 = fmaf(wb, blo(gb.y), b2); b3 = fmaf(wb, bhi(gb.y), b3);
        b4 = fmaf(wb, blo(gb.z), b4); b5 = fmaf(wb, bhi(gb.z), b5);
        b6 = fmaf(wb, blo(gb.w), b6); b7 = fmaf(wb, bhi(gb.w), b7);
    }
    if (e < e1) {
        uint ea = ec[e];
        uint4 ga = in[(ea & 0xFFFFu) * 4 + u];
        float wa = bhi(ea);
        a0 = fmaf(wa, blo(ga.x), a0); a1 = fmaf(wa, bhi(ga.x), a1);
        a2 = fmaf(wa, blo(ga.y), a2); a3 = fmaf(wa, bhi(ga.y), a3);
        a4 = fmaf(wa, blo(ga.z), a4); a5 = fmaf(wa, bhi(ga.z), a5);
        a6 = fmaf(wa, blo(ga.w), a6); a7 = fmaf(wa, bhi(ga.w), a7);
    }
    a0 += b0; a1 += b1; a2 += b2; a3 += b3;
    a4 += b4; a5 += b5; a6 += b6; a7 += b7;
    uint4 res;
    if (PHASE == 1) {
        res.x = (uint)f2bf(2.f * a0) | ((uint)f2bf(2.f * a1) << 16);
        res.y = (uint)f2bf(2.f * a2) | ((uint)f2bf(2.f * a3) << 16);
        res.z = (uint)f2bf(2.f * a4) | ((uint)f2bf(2.f * a5) << 16);
        res.w = (uint)f2bf(2.f * a6) | ((uint)f2bf(2.f * a7) << 16);
    } else {
        const uint4* prev = (const uint4*)((sign ? n_prev : p_prev) + q * QSZU);
        uint4 pu = prev[r * 4 + u];
        float r0 = fmaf(1.875f, a0, -1.6875f * blo(pu.x));
        float r1 = fmaf(1.875f, a1, -1.6875f * bhi(pu.x));
        float r2 = fmaf(1.875f, a2, -1.6875f * blo(pu.y));
        float r3 = fmaf(1.875f, a3, -1.6875f * bhi(pu.y));
        float r4 = fmaf(1.875f, a4, -1.6875f * blo(pu.z));
        float r5 = fmaf(1.875f, a5, -1.6875f * bhi(pu.z));
        float r6 = fmaf(1.875f, a6, -1.6875f * blo(pu.w));
        float r7 = fmaf(1.875f, a7, -1.6875f * bhi(pu.w));
        res.x = (uint)f2bf(r0) | ((uint)f2bf(r1) << 16);
        res.y = (uint)f2bf(r2) | ((uint)f2bf(r3) << 16);
        res.z = (uint)f2bf(r4) | ((uint)f2bf(r5) << 16);
        res.w = (uint)f2bf(r6) | ((uint)f2bf(r7) << 16);
    }
    out[r * 4 + u] = res;
}

// ---------------- batch stats for pos & neg (quarter-blocked bf16 input) ----------------

__global__ __launch_bounds__(256) void stats2_k(const ushort* __restrict__ pos,
                                                const ushort* __restrict__ neg,
                                                float* __restrict__ sums,
                                                float* __restrict__ sumsq) {
    int b = blockIdx.x;            // 626 blocks
    int sign = b >= 313;
    int blk = b - sign * 313;
    const ushort* buf = sign ? neg : pos;
    int c = threadIdx.x & 127, half = threadIdx.x >> 7;
    int qq = c >> 5, cc = c & 31;
    const ushort* base = buf + (long)qq * QSZ16 + cc;
    int r0 = blk * 128;
    int rend = r0 + 128; if (rend > NNODES) rend = NNODES;
    float s = 0.f, s2 = 0.f;
    for (int r = r0 + half; r < rend; r += 2) {
        float v = bf2f(base[r * 32]);
        s += v;
        s2 = fmaf(v, v, s2);
    }
    __shared__ float sh[256], sh2[256];
    sh[threadIdx.x] = s; sh2[threadIdx.x] = s2;
    __syncthreads();
    if (threadIdx.x < 128) {
        int sb = 128 + sign * 128;
        atomicAdd(&sums[sb + c],  sh[c]  + sh[c + 128]);
        atomicAdd(&sumsq[sb + c], sh2[c] + sh2[c + 128]);
    }
}

// ---------------- final MFMA GEMM K=384: BN-finalize + BN+PReLU+concat + row-norm ----

__global__ __launch_bounds__(256) void mfma_gemm_mlp_k(const ushort* __restrict__ org,
                                                       const ushort* __restrict__ pos,
                                                       const ushort* __restrict__ neg,
                                                       const float* __restrict__ sums,
                                                       const float* __restrict__ sumsq,
                                                       const float* __restrict__ g0,
                                                       const float* __restrict__ be0,
                                                       const float* __restrict__ g1,
                                                       const float* __restrict__ be1,
                                                       const float* __restrict__ g2,
                                                       const float* __restrict__ be2,
                                                       const float* __restrict__ prelu_w,
                                                       const ushort* __restrict__ Bp,
                                                       float* __restrict__ Out) {
    __shared__ __align__(16) float bnl[768];
    int tid = threadIdx.x;
    for (int i = tid; i < 384; i += 256) {
        int s = i >> 7, c = i & 127;
        float mean = sums[i] * (1.f / NNODES);
        float var  = sumsq[i] * (1.f / NNODES) - mean * mean;
        const float* g = (s == 0) ? g0 : (s == 1) ? g1 : g2;
        const float* b = (s == 0) ? be0 : (s == 1) ? be1 : be2;
        float sc = g[c] * rsqrtf(var + 1e-5f);
        bnl[s * 256 + c]       = sc;
        bnl[s * 256 + 128 + c] = b[c] - mean * sc;
    }
    __syncthreads();
    int lane = tid & 63, wave = tid >> 6;
    long rbase = (long)blockIdx.x * 64 + wave * 16;
    int r = lane & 15, kg = lane >> 4;
    float pw = prelu_w[0];
    facc acc[8];
#pragma unroll
    for (int t = 0; t < 8; ++t) acc[t] = (facc){0.f, 0.f, 0.f, 0.f};
    const bfrag* Bq = (const bfrag*)Bp + lane;
#pragma unroll
    for (int ks = 0; ks < 12; ++ks) {
        int c = ks * 32 + kg * 8;          // concat column of first elem
        int s = c >> 7;
        int off = c & 127;
        const ushort* src = (s == 0) ? org : (s == 1) ? pos : neg;
        const uint* srcu = (const uint*)src;
        uint4 u = *(const uint4*)(srcu + (long)(off >> 5) * QSZU + (rbase + r) * 16 + ((off & 31) >> 1));
        float4 sc_lo = *(const float4*)(bnl + s * 256 + off);
        float4 sc_hi = *(const float4*)(bnl + s * 256 + off + 4);
        float4 sh_lo = *(const float4*)(bnl + s * 256 + 128 + off);
        float4 sh_hi = *(const float4*)(bnl + s * 256 + 128 + off + 4);
        uint uu[4] = {u.x, u.y, u.z, u.w};
        float scv[8] = {sc_lo.x, sc_lo.y, sc_lo.z, sc_lo.w, sc_hi.x, sc_hi.y, sc_hi.z, sc_hi.w};
        float shv[8] = {sh_lo.x, sh_lo.y, sh_lo.z, sh_lo.w, sh_hi.x, sh_hi.y, sh_hi.z, sh_hi.w};
        bfu av;
#pragma unroll
        for (int k = 0; k < 4; ++k) {
            float vx = __uint_as_float(uu[k] << 16);
            float vy = __uint_as_float(uu[k] & 0xFFFF0000u);
            float ox = fmaf(vx, scv[2 * k],     shv[2 * k]);     ox = (ox >= 0.f) ? ox : pw * ox;
            float oy = fmaf(vy, scv[2 * k + 1], shv[2 * k + 1]); oy = (oy >= 0.f) ? oy : pw * oy;
            av.u[k] = (uint)f2bf(ox) | ((uint)f2bf(oy) << 16);
        }
#pragma unroll
        for (int t = 0; t < 8; ++t)
            acc[t] = __builtin_amdgcn_mfma_f32_16x16x32_bf16(av.v, Bq[(ks * 8 + t) * 64], acc[t], 0, 0, 0);
    }
    long orow = rbase + kg * 4;
#pragma unroll
    for (int j = 0; j < 4; ++j) {
        float ss = 0.f;
#pragma unroll
        for (int t = 0; t < 8; ++t) ss = fmaf(acc[t][j], acc[t][j], ss);
        ss += __shfl_xor(ss, 1);
        ss += __shfl_xor(ss, 2);
        ss += __shfl_xor(ss, 4);
        ss += __shfl_xor(ss, 8);
        float inv = 1.f / fmaxf(sqrtf(ss), 1e-12f);
#pragma unroll
        for (int t = 0; t < 8; ++t)
            Out[(orow + j) * 128 + 16 * t + r] = acc[t][j] * inv;
    }
}

// ---------------- launch ----------------

extern "C" void kernel_launch(void* const* d_in, const int* in_sizes, int n_in,
                              void* d_out, int out_size, void* d_ws, size_t ws_size,
                              hipStream_t stream) {
    const float* x       = (const float*)d_in[0];
    const int*   pos_idx = (const int*)d_in[1];
    const float* pos_w   = (const float*)d_in[2];
    const int*   neg_idx = (const int*)d_in[3];
    const float* neg_w   = (const float*)d_in[4];
    const float* W_org   = (const float*)d_in[5];
    const float* W_pos   = (const float*)d_in[6];
    const float* W_neg   = (const float*)d_in[7];
    const float* g_org   = (const float*)d_in[8];
    const float* b_org   = (const float*)d_in[9];
    const float* g_pos   = (const float*)d_in[10];
    const float* b_pos   = (const float*)d_in[11];
    const float* g_neg   = (const float*)d_in[12];
    const float* b_neg   = (const float*)d_in[13];
    const float* prelu_w = (const float*)d_in[14];
    const float* W_mlp   = (const float*)d_in[15];
    float* out = (float*)d_out;

    char* ws = (char*)d_ws;
    const size_t FB = (size_t)NNODES * 128 * 2;        // 10,240,000 B per feature buffer
    ushort* org0b = (ushort*)(ws);
    ushort* p0b   = (ushort*)(ws + FB);
    ushort* n0b   = (ushort*)(ws + 2 * FB);
    int2* edges   = (int2*)(ws + 3 * FB);              // staging, 14,080,000 B
    uint* ecomp   = (uint*)(ws + 3 * FB + 14080000);   // compressed, 7,040,000 B
    char* small   = ws + 3 * FB + 14080000 + 7040000;
    int* ecnt     = (int*)small;                       // 5000 -> pad 5120
    float* sums   = (float*)(small + 5120);            // 1536
    float* sumsq  = (float*)(small + 5120 + 1536);     // 1536 (memset 0..8192)
    int2* rp2     = (int2*)(small + 8192);             // 640,000
    ushort* Wb    = (ushort*)(small + 8192 + 640000);  // 196,608 B
    uint* t1_pos  = (uint*)d_out;                      // blocked bf16 scratch halves of d_out
    uint* t1_neg  = (uint*)d_out + 4 * QSZU;

    hipMemsetAsync(small, 0, 8192, stream);

    prep_k<<<PBLKS + 384, 256, 0, stream>>>(pos_idx, pos_w, neg_idx, neg_w, ecnt, edges,
                                            W_org, W_pos, W_neg, W_mlp, Wb);

    mid_k<<<2 * NBUCK + 625, 256, 0, stream>>>(ecnt, edges, ecomp, rp2,
                                               x, Wb, Wb + 16384, Wb + 32768,
                                               org0b, p0b, n0b, sums, sumsq);

    // Jacobi (a=b=1, K=3): x1 = 2*A@x0 ; x2 = 1.875*A@x1 - 1.6875*x0
    spmmg_k<1><<<5000, 256, 0, stream>>>(rp2, ecomp,
        (const uint*)p0b, (const uint*)n0b, nullptr, nullptr, t1_pos, t1_neg);
    spmmg_k<2><<<5000, 256, 0, stream>>>(rp2, ecomp,
        t1_pos, t1_neg, (const uint*)p0b, (const uint*)n0b, (uint*)p0b, (uint*)n0b);

    stats2_k<<<626, 256, 0, stream>>>(p0b, n0b, sums, sumsq);
    mfma_gemm_mlp_k<<<625, 256, 0, stream>>>(org0b, p0b, n0b, sums, sumsq,
                                             g_org, b_org, g_pos, b_pos, g_neg, b_neg,
                                             prelu_w, Wb + 49152, out);

    (void)in_sizes; (void)n_in; (void)out_size; (void)ws_size;
}

// Round 19
// 201.071 us; speedup vs baseline: 1.0625x; 1.0362x over previous
//
#include <hip/hip_runtime.h>

#define NNODES 40000
#define NEDGE  640000
#define NBUCK  625          // buckets per sign, 64 rows each
#define ECAP   1408         // per-bucket capacity (mean 1024, sd ~32)
#define QSZ16  1280000      // ushorts per quarter table (40000*32)
#define QSZU   640000       // uints per quarter table
#define PCHUNK 4096         // edges per partition block
#define PBLKS  313          // ceil(2*NEDGE / PCHUNK)

typedef __attribute__((ext_vector_type(8))) short bfrag;
typedef __attribute__((ext_vector_type(4))) float facc;

union bfu { bfrag v; uint u[4]; };

__device__ inline ushort f2bf(float f) {
    uint u = __float_as_uint(f);
    return (ushort)((u + 0x7FFFu + ((u >> 16) & 1u)) >> 16);
}
__device__ inline float bf2f(ushort h) {
    return __uint_as_float(((uint)h) << 16);
}
__device__ inline float blo(uint u) { return __uint_as_float(u << 16); }
__device__ inline float bhi(uint u) { return __uint_as_float(u & 0xFFFF0000u); }

// ---------------- fused: edge partition (blocks 0..312) + W pack (blocks 313..696) ----

__global__ __launch_bounds__(256) void prep_k(const int* __restrict__ pos_idx,
                                              const float* __restrict__ pos_w,
                                              const int* __restrict__ neg_idx,
                                              const float* __restrict__ neg_w,
                                              int* __restrict__ ecnt,
                                              int2* __restrict__ edges,
                                              const float* __restrict__ Wo,
                                              const float* __restrict__ Wp,
                                              const float* __restrict__ Wn,
                                              const float* __restrict__ Wm,
                                              ushort* __restrict__ wout) {
    __shared__ int lhist[2 * NBUCK];
    __shared__ int lbase[2 * NBUCK];
    __shared__ ushort rows_s[PCHUNK];
    if (blockIdx.x >= PBLKS) {
        // -------- W pack path --------
        int idx = (blockIdx.x - PBLKS) * 256 + threadIdx.x;   // 0..98303
        const float* W;
        ushort* dst;
        int local;
        if (idx < 49152) {
            int m = idx >> 14;
            local = idx & 16383;
            W = (m == 0) ? Wo : (m == 1) ? Wp : Wn;
            dst = wout + m * 16384;
        } else {
            local = idx - 49152;
            W = Wm;
            dst = wout + 49152;
        }
        int j = local & 7, l = (local >> 3) & 63, t = (local >> 9) & 7, ks = local >> 12;
        int k = ks * 32 + (l >> 4) * 8 + j;
        int c = (l & 15) + 16 * t;
        dst[local] = f2bf(W[k * 128 + c]);
        return;
    }
    // -------- partition path --------
    long g0 = (long)blockIdx.x * PCHUNK;
    for (int i = threadIdx.x; i < 2 * NBUCK; i += 256) lhist[i] = 0;
    __syncthreads();
#pragma unroll
    for (int i = 0; i < 16; ++i) {
        long g = g0 + i * 256 + threadIdx.x;
        if (g < 2 * NEDGE) {
            int sign = g >= NEDGE;
            int e = (int)(g - (long)sign * NEDGE);
            int row = sign ? neg_idx[e] : pos_idx[e];
            rows_s[i * 256 + threadIdx.x] = (ushort)row;
            atomicAdd(&lhist[sign * NBUCK + (row >> 6)], 1);
        }
    }
    __syncthreads();
    for (int b = threadIdx.x; b < 2 * NBUCK; b += 256) {
        int c = lhist[b];
        lbase[b] = c ? atomicAdd(&ecnt[b], c) : 0;
        lhist[b] = 0;
    }
    __syncthreads();
#pragma unroll
    for (int i = 0; i < 16; ++i) {
        long g = g0 + i * 256 + threadIdx.x;
        if (g < 2 * NEDGE) {
            int sign = g >= NEDGE;
            int e = (int)(g - (long)sign * NEDGE);
            int row = rows_s[i * 256 + threadIdx.x];
            int col = sign ? neg_idx[NEDGE + e] : pos_idx[NEDGE + e];
            float wv = sign ? neg_w[e] : pos_w[e];
            int b = sign * NBUCK + (row >> 6);
            int off = lbase[b] + atomicAdd(&lhist[b], 1);
            if (off < ECAP)
                edges[(long)b * ECAP + off] =
                    make_int2((int)((uint)col | ((uint)(row & 63) << 16)), __float_as_int(wv));
        }
    }
}

// ---------------- bucket-local counting sort -> compressed CSR ----------------

__global__ __launch_bounds__(256) void bucket_csr_k(const int* __restrict__ ecnt,
                                                    const int2* __restrict__ edges,
                                                    uint* __restrict__ ecomp,
                                                    int2* __restrict__ rp2) {
    __shared__ int2 stage[ECAP];
    __shared__ int hist[64];
    __shared__ int base_[64];
    int b = blockIdx.x;
    int tid = threadIdx.x;
    int cnt = ecnt[b]; if (cnt > ECAP) cnt = ECAP;
    if (tid < 64) hist[tid] = 0;
    __syncthreads();
    long e0 = (long)b * ECAP;
    for (int i = tid; i < cnt; i += 256) {
        int2 e = edges[e0 + i];
        stage[i] = e;
        atomicAdd(&hist[((uint)e.x >> 16) & 63u], 1);
    }
    __syncthreads();
    if (tid < 64) {
        int v = hist[tid];
        int s = v;
#pragma unroll
        for (int off = 1; off < 64; off <<= 1) {
            int t = __shfl_up(s, off);
            if ((tid & 63) >= off) s += t;
        }
        int excl = s - v;
        base_[tid] = excl;
        int sign = b >= NBUCK;
        int r = (b - sign * NBUCK) * 64 + tid;
        rp2[sign * NNODES + r] = make_int2((int)(e0 + excl), (int)(e0 + excl + v));
        hist[tid] = 0;   // reuse as cursor
    }
    __syncthreads();
    for (int i = tid; i < cnt; i += 256) {
        int2 e = stage[i];
        int rl = ((uint)e.x >> 16) & 63u;
        int pos = base_[rl] + atomicAdd(&hist[rl], 1);
        ecomp[e0 + pos] = ((uint)e.x & 0xFFFFu) |
                          ((uint)f2bf(__int_as_float(e.y)) << 16);
    }
}

// ---------------- fused triple MFMA GEMM: x(f32) @ {W_org,W_pos,W_neg} ----------------
// outputs quarter-blocked bf16; fused per-channel stats for org.

__global__ __launch_bounds__(256) void mfma_gemm3_k(const float* __restrict__ x,
                                                    const ushort* __restrict__ B0,
                                                    const ushort* __restrict__ B1,
                                                    const ushort* __restrict__ B2,
                                                    ushort* __restrict__ O0,
                                                    ushort* __restrict__ O1,
                                                    ushort* __restrict__ O2,
                                                    float* __restrict__ sums,
                                                    float* __restrict__ sumsq) {
    __shared__ float cs[128], cq[128];
    int tid = threadIdx.x;
    int lane = tid & 63, wave = tid >> 6;
    if (tid < 128) { cs[tid] = 0.f; cq[tid] = 0.f; }
    __syncthreads();
    long rbase = (long)blockIdx.x * 64 + wave * 16;
    int r = lane & 15, kg = lane >> 4;
    const float* xr = x + (rbase + r) * 128 + kg * 8;
    bfrag a[4];
#pragma unroll
    for (int ks = 0; ks < 4; ++ks) {
        float4 lo = *(const float4*)(xr + ks * 32);
        float4 hi = *(const float4*)(xr + ks * 32 + 4);
        bfu t;
        t.u[0] = (uint)f2bf(lo.x) | ((uint)f2bf(lo.y) << 16);
        t.u[1] = (uint)f2bf(lo.z) | ((uint)f2bf(lo.w) << 16);
        t.u[2] = (uint)f2bf(hi.x) | ((uint)f2bf(hi.y) << 16);
        t.u[3] = (uint)f2bf(hi.z) | ((uint)f2bf(hi.w) << 16);
        a[ks] = t.v;
    }
    const ushort* Bs[3] = {B0, B1, B2};
    ushort* Os[3] = {O0, O1, O2};
    long orow = rbase + kg * 4;
#pragma unroll
    for (int m = 0; m < 3; ++m) {
        const bfrag* Bq = (const bfrag*)Bs[m] + lane;
        facc acc[8];
#pragma unroll
        for (int t = 0; t < 8; ++t) acc[t] = (facc){0.f, 0.f, 0.f, 0.f};
#pragma unroll
        for (int ks = 0; ks < 4; ++ks)
#pragma unroll
            for (int t = 0; t < 8; ++t)
                acc[t] = __builtin_amdgcn_mfma_f32_16x16x32_bf16(a[ks], Bq[(ks * 8 + t) * 64], acc[t], 0, 0, 0);
        ushort* O = Os[m];
#pragma unroll
        for (int t = 0; t < 8; ++t) {
            float s_ = 0.f, q_ = 0.f;
            // channel c = 16t + r -> blocked: q = t>>1, cc = (t&1)*16 + r
            long qb = (long)(t >> 1) * QSZ16 + (t & 1) * 16 + r;
#pragma unroll
            for (int j = 0; j < 4; ++j) {
                ushort bv = f2bf(acc[t][j]);
                O[qb + (orow + j) * 32] = bv;
                if (m == 0) {
                    float fv = bf2f(bv);
                    s_ += fv;
                    q_ = fmaf(fv, fv, q_);
                }
            }
            if (m == 0) {
                atomicAdd(&cs[16 * t + r], s_);
                atomicAdd(&cq[16 * t + r], q_);
            }
        }
    }
    __syncthreads();
    if (tid < 128) {
        atomicAdd(&sums[tid], cs[tid]);
        atomicAdd(&sumsq[tid], cq[tid]);
    }
}

// ---------------- quarter-blocked SpMM: 16 rows/wave x 4 lanes, uint4 gathers ----------
// grp = blockIdx.x & 7 pins each (sign,quarter) group to one XCD (2.56 MB table
// L2-resident). Wave = 16 rows x 4 lanes; each 4-lane group walks its own row's
// edges (unroll-2, proven schedule) with uint4 (16 B) gathers -> 2 KB in
// flight per wave. Zero cross-lane reduce; coalesced 1 KB wave stores.

template<int PHASE>
__global__ __launch_bounds__(256) void spmmg_k(const int2* __restrict__ rp2,
                                               const uint* __restrict__ ec,
                                               const uint* __restrict__ p_in,
                                               const uint* __restrict__ n_in,
                                               const uint* __restrict__ p_prev,
                                               const uint* __restrict__ n_prev,
                                               uint* __restrict__ p_out,
                                               uint* __restrict__ n_out) {
    int grp = blockIdx.x & 7;
    int rg  = blockIdx.x >> 3;          // 0..624
    int sign = grp >> 2, q = grp & 3;
    int tid = threadIdx.x;
    int w = tid >> 6, lane = tid & 63;
    int u = lane & 3;                   // uint4 index (8 bf16 channels)
    int rl = lane >> 2;                 // row within wave (0..15)
    const uint4* in  = (const uint4*)((sign ? n_in : p_in) + q * QSZU);
    uint4* out = (uint4*)((sign ? n_out : p_out) + q * QSZU);
    int r = rg * 64 + w * 16 + rl;
    int2 se = rp2[sign * NNODES + r];
    float a0 = 0.f, a1 = 0.f, a2 = 0.f, a3 = 0.f;
    float a4 = 0.f, a5 = 0.f, a6 = 0.f, a7 = 0.f;
    float b0 = 0.f, b1 = 0.f, b2 = 0.f, b3 = 0.f;
    float b4 = 0.f, b5 = 0.f, b6 = 0.f, b7 = 0.f;
    int e = se.x, e1 = se.y;
    for (; e + 2 <= e1; e += 2) {
        uint ea = ec[e], eb = ec[e + 1];
        uint4 ga = in[(ea & 0xFFFFu) * 4 + u];
        uint4 gb = in[(eb & 0xFFFFu) * 4 + u];
        float wa = bhi(ea), wb = bhi(eb);
        a0 = fmaf(wa, blo(ga.x), a0); a1 = fmaf(wa, bhi(ga.x), a1);
        a2 = fmaf(wa, blo(ga.y), a2); a3 = fmaf(wa, bhi(ga.y), a3);
        a4 = fmaf(wa, blo(ga.z), a4); a5 = fmaf(wa, bhi(ga.z), a5);
        a6 = fmaf(wa, blo(ga.w), a6); a7 = fmaf(wa, bhi(ga.w), a7);
        b0 = fmaf(wb, blo(gb.x), b0); b1 = fmaf(wb, bhi(gb.x), b1);
        b2 = fmaf(wb, blo(gb.y), b2); b3 = fmaf(wb, bhi(gb.y), b3);
        b4 = fmaf(wb, blo(gb.z), b4); b5 = fmaf(wb, bhi(gb.z), b5);
        b6 = fmaf(wb, blo(gb.w), b6); b7 = fmaf(wb, bhi(gb.w), b7);
    }
    if (e < e1) {
        uint ea = ec[e];
        uint4 ga = in[(ea & 0xFFFFu) * 4 + u];
        float wa = bhi(ea);
        a0 = fmaf(wa, blo(ga.x), a0); a1 = fmaf(wa, bhi(ga.x), a1);
        a2 = fmaf(wa, blo(ga.y), a2); a3 = fmaf(wa, bhi(ga.y), a3);
        a4 = fmaf(wa, blo(ga.z), a4); a5 = fmaf(wa, bhi(ga.z), a5);
        a6 = fmaf(wa, blo(ga.w), a6); a7 = fmaf(wa, bhi(ga.w), a7);
    }
    a0 += b0; a1 += b1; a2 += b2; a3 += b3;
    a4 += b4; a5 += b5; a6 += b6; a7 += b7;
    uint4 res;
    if (PHASE == 1) {
        res.x = (uint)f2bf(2.f * a0) | ((uint)f2bf(2.f * a1) << 16);
        res.y = (uint)f2bf(2.f * a2) | ((uint)f2bf(2.f * a3) << 16);
        res.z = (uint)f2bf(2.f * a4) | ((uint)f2bf(2.f * a5) << 16);
        res.w = (uint)f2bf(2.f * a6) | ((uint)f2bf(2.f * a7) << 16);
    } else {
        const uint4* prev = (const uint4*)((sign ? n_prev : p_prev) + q * QSZU);
        uint4 pu = prev[r * 4 + u];
        float r0 = fmaf(1.875f, a0, -1.6875f * blo(pu.x));
        float r1 = fmaf(1.875f, a1, -1.6875f * bhi(pu.x));
        float r2 = fmaf(1.875f, a2, -1.6875f * blo(pu.y));
        float r3 = fmaf(1.875f, a3, -1.6875f * bhi(pu.y));
        float r4 = fmaf(1.875f, a4, -1.6875f * blo(pu.z));
        float r5 = fmaf(1.875f, a5, -1.6875f * bhi(pu.z));
        float r6 = fmaf(1.875f, a6, -1.6875f * blo(pu.w));
        float r7 = fmaf(1.875f, a7, -1.6875f * bhi(pu.w));
        res.x = (uint)f2bf(r0) | ((uint)f2bf(r1) << 16);
        res.y = (uint)f2bf(r2) | ((uint)f2bf(r3) << 16);
        res.z = (uint)f2bf(r4) | ((uint)f2bf(r5) << 16);
        res.w = (uint)f2bf(r6) | ((uint)f2bf(r7) << 16);
    }
    out[r * 4 + u] = res;
}

// ---------------- batch stats for pos & neg (quarter-blocked bf16 input) ----------------

__global__ __launch_bounds__(256) void stats2_k(const ushort* __restrict__ pos,
                                                const ushort* __restrict__ neg,
                                                float* __restrict__ sums,
                                                float* __restrict__ sumsq) {
    int b = blockIdx.x;            // 626 blocks
    int sign = b >= 313;
    int blk = b - sign * 313;
    const ushort* buf = sign ? neg : pos;
    int c = threadIdx.x & 127, half = threadIdx.x >> 7;
    int qq = c >> 5, cc = c & 31;
    const ushort* base = buf + (long)qq * QSZ16 + cc;
    int r0 = blk * 128;
    int rend = r0 + 128; if (rend > NNODES) rend = NNODES;
    float s = 0.f, s2 = 0.f;
    for (int r = r0 + half; r < rend; r += 2) {
        float v = bf2f(base[r * 32]);
        s += v;
        s2 = fmaf(v, v, s2);
    }
    __shared__ float sh[256], sh2[256];
    sh[threadIdx.x] = s; sh2[threadIdx.x] = s2;
    __syncthreads();
    if (threadIdx.x < 128) {
        int sb = 128 + sign * 128;
        atomicAdd(&sums[sb + c],  sh[c]  + sh[c + 128]);
        atomicAdd(&sumsq[sb + c], sh2[c] + sh2[c + 128]);
    }
}

// ---------------- final MFMA GEMM K=384: BN-finalize + BN+PReLU+concat + row-norm ----

__global__ __launch_bounds__(256) void mfma_gemm_mlp_k(const ushort* __restrict__ org,
                                                       const ushort* __restrict__ pos,
                                                       const ushort* __restrict__ neg,
                                                       const float* __restrict__ sums,
                                                       const float* __restrict__ sumsq,
                                                       const float* __restrict__ g0,
                                                       const float* __restrict__ be0,
                                                       const float* __restrict__ g1,
                                                       const float* __restrict__ be1,
                                                       const float* __restrict__ g2,
                                                       const float* __restrict__ be2,
                                                       const float* __restrict__ prelu_w,
                                                       const ushort* __restrict__ Bp,
                                                       float* __restrict__ Out) {
    __shared__ __align__(16) float bnl[768];
    int tid = threadIdx.x;
    for (int i = tid; i < 384; i += 256) {
        int s = i >> 7, c = i & 127;
        float mean = sums[i] * (1.f / NNODES);
        float var  = sumsq[i] * (1.f / NNODES) - mean * mean;
        const float* g = (s == 0) ? g0 : (s == 1) ? g1 : g2;
        const float* b = (s == 0) ? be0 : (s == 1) ? be1 : be2;
        float sc = g[c] * rsqrtf(var + 1e-5f);
        bnl[s * 256 + c]       = sc;
        bnl[s * 256 + 128 + c] = b[c] - mean * sc;
    }
    __syncthreads();
    int lane = tid & 63, wave = tid >> 6;
    long rbase = (long)blockIdx.x * 64 + wave * 16;
    int r = lane & 15, kg = lane >> 4;
    float pw = prelu_w[0];
    facc acc[8];
#pragma unroll
    for (int t = 0; t < 8; ++t) acc[t] = (facc){0.f, 0.f, 0.f, 0.f};
    const bfrag* Bq = (const bfrag*)Bp + lane;
#pragma unroll
    for (int ks = 0; ks < 12; ++ks) {
        int c = ks * 32 + kg * 8;          // concat column of first elem
        int s = c >> 7;
        int off = c & 127;
        const ushort* src = (s == 0) ? org : (s == 1) ? pos : neg;
        const uint* srcu = (const uint*)src;
        uint4 u = *(const uint4*)(srcu + (long)(off >> 5) * QSZU + (rbase + r) * 16 + ((off & 31) >> 1));
        float4 sc_lo = *(const float4*)(bnl + s * 256 + off);
        float4 sc_hi = *(const float4*)(bnl + s * 256 + off + 4);
        float4 sh_lo = *(const float4*)(bnl + s * 256 + 128 + off);
        float4 sh_hi = *(const float4*)(bnl + s * 256 + 128 + off + 4);
        uint uu[4] = {u.x, u.y, u.z, u.w};
        float scv[8] = {sc_lo.x, sc_lo.y, sc_lo.z, sc_lo.w, sc_hi.x, sc_hi.y, sc_hi.z, sc_hi.w};
        float shv[8] = {sh_lo.x, sh_lo.y, sh_lo.z, sh_lo.w, sh_hi.x, sh_hi.y, sh_hi.z, sh_hi.w};
        bfu av;
#pragma unroll
        for (int k = 0; k < 4; ++k) {
            float vx = __uint_as_float(uu[k] << 16);
            float vy = __uint_as_float(uu[k] & 0xFFFF0000u);
            float ox = fmaf(vx, scv[2 * k],     shv[2 * k]);     ox = (ox >= 0.f) ? ox : pw * ox;
            float oy = fmaf(vy, scv[2 * k + 1], shv[2 * k + 1]); oy = (oy >= 0.f) ? oy : pw * oy;
            av.u[k] = (uint)f2bf(ox) | ((uint)f2bf(oy) << 16);
        }
#pragma unroll
        for (int t = 0; t < 8; ++t)
            acc[t] = __builtin_amdgcn_mfma_f32_16x16x32_bf16(av.v, Bq[(ks * 8 + t) * 64], acc[t], 0, 0, 0);
    }
    long orow = rbase + kg * 4;
#pragma unroll
    for (int j = 0; j < 4; ++j) {
        float ss = 0.f;
#pragma unroll
        for (int t = 0; t < 8; ++t) ss = fmaf(acc[t][j], acc[t][j], ss);
        ss += __shfl_xor(ss, 1);
        ss += __shfl_xor(ss, 2);
        ss += __shfl_xor(ss, 4);
        ss += __shfl_xor(ss, 8);
        float inv = 1.f / fmaxf(sqrtf(ss), 1e-12f);
#pragma unroll
        for (int t = 0; t < 8; ++t)
            Out[(orow + j) * 128 + 16 * t + r] = acc[t][j] * inv;
    }
}

// ---------------- launch ----------------

extern "C" void kernel_launch(void* const* d_in, const int* in_sizes, int n_in,
                              void* d_out, int out_size, void* d_ws, size_t ws_size,
                              hipStream_t stream) {
    const float* x       = (const float*)d_in[0];
    const int*   pos_idx = (const int*)d_in[1];
    const float* pos_w   = (const float*)d_in[2];
    const int*   neg_idx = (const int*)d_in[3];
    const float* neg_w   = (const float*)d_in[4];
    const float* W_org   = (const float*)d_in[5];
    const float* W_pos   = (const float*)d_in[6];
    const float* W_neg   = (const float*)d_in[7];
    const float* g_org   = (const float*)d_in[8];
    const float* b_org   = (const float*)d_in[9];
    const float* g_pos   = (const float*)d_in[10];
    const float* b_pos   = (const float*)d_in[11];
    const float* g_neg   = (const float*)d_in[12];
    const float* b_neg   = (const float*)d_in[13];
    const float* prelu_w = (const float*)d_in[14];
    const float* W_mlp   = (const float*)d_in[15];
    float* out = (float*)d_out;

    char* ws = (char*)d_ws;
    const size_t FB = (size_t)NNODES * 128 * 2;        // 10,240,000 B per feature buffer
    ushort* org0b = (ushort*)(ws);
    ushort* p0b   = (ushort*)(ws + FB);
    ushort* n0b   = (ushort*)(ws + 2 * FB);
    int2* edges   = (int2*)(ws + 3 * FB);              // staging, 14,080,000 B
    uint* ecomp   = (uint*)(ws + 3 * FB + 14080000);   // compressed, 7,040,000 B
    char* small   = ws + 3 * FB + 14080000 + 7040000;
    int* ecnt     = (int*)small;                       // 5000 -> pad 5120
    float* sums   = (float*)(small + 5120);            // 1536
    float* sumsq  = (float*)(small + 5120 + 1536);     // 1536 (memset 0..8192)
    int2* rp2     = (int2*)(small + 8192);             // 640,000
    ushort* Wb    = (ushort*)(small + 8192 + 640000);  // 196,608 B
    uint* t1_pos  = (uint*)d_out;                      // blocked bf16 scratch halves of d_out
    uint* t1_neg  = (uint*)d_out + 4 * QSZU;

    hipMemsetAsync(small, 0, 8192, stream);

    prep_k<<<PBLKS + 384, 256, 0, stream>>>(pos_idx, pos_w, neg_idx, neg_w, ecnt, edges,
                                            W_org, W_pos, W_neg, W_mlp, Wb);
    bucket_csr_k<<<2 * NBUCK, 256, 0, stream>>>(ecnt, edges, ecomp, rp2);

    mfma_gemm3_k<<<625, 256, 0, stream>>>(x, Wb, Wb + 16384, Wb + 32768,
                                          org0b, p0b, n0b, sums, sumsq);

    // Jacobi (a=b=1, K=3): x1 = 2*A@x0 ; x2 = 1.875*A@x1 - 1.6875*x0
    spmmg_k<1><<<5000, 256, 0, stream>>>(rp2, ecomp,
        (const uint*)p0b, (const uint*)n0b, nullptr, nullptr, t1_pos, t1_neg);
    spmmg_k<2><<<5000, 256, 0, stream>>>(rp2, ecomp,
        t1_pos, t1_neg, (const uint*)p0b, (const uint*)n0b, (uint*)p0b, (uint*)n0b);

    stats2_k<<<626, 256, 0, stream>>>(p0b, n0b, sums, sumsq);
    mfma_gemm_mlp_k<<<625, 256, 0, stream>>>(org0b, p0b, n0b, sums, sumsq,
                                             g_org, b_org, g_pos, b_pos, g_neg, b_neg,
                                             prelu_w, Wb + 49152, out);

    (void)in_sizes; (void)n_in; (void)out_size; (void)ws_size;
}

// Round 20
// 193.112 us; speedup vs baseline: 1.1063x; 1.0412x over previous
//
#include <hip/hip_runtime.h>

#define NNODES 40000
#define NEDGE  640000
#define NBUCK  625          // buckets per sign, 64 rows each
#define ECAP   1408         // per-bucket capacity (mean 1024, sd ~32)
#define QSZ16  1280000      // ushorts per quarter table (40000*32)
#define QSZU   640000       // uints per quarter table
#define PCHUNK 4096         // edges per partition block
#define PBLKS  313          // ceil(2*NEDGE / PCHUNK)

typedef __attribute__((ext_vector_type(8))) short bfrag;
typedef __attribute__((ext_vector_type(4))) float facc;

union bfu { bfrag v; uint u[4]; };

__device__ inline ushort f2bf(float f) {
    uint u = __float_as_uint(f);
    return (ushort)((u + 0x7FFFu + ((u >> 16) & 1u)) >> 16);
}
__device__ inline float bf2f(ushort h) {
    return __uint_as_float(((uint)h) << 16);
}
__device__ inline float blo(uint u) { return __uint_as_float(u << 16); }
__device__ inline float bhi(uint u) { return __uint_as_float(u & 0xFFFF0000u); }

// ---------------- fused: edge partition (blocks 0..312) + W pack (blocks 313..696) ----

__global__ __launch_bounds__(256) void prep_k(const int* __restrict__ pos_idx,
                                              const float* __restrict__ pos_w,
                                              const int* __restrict__ neg_idx,
                                              const float* __restrict__ neg_w,
                                              int* __restrict__ ecnt,
                                              int2* __restrict__ edges,
                                              const float* __restrict__ Wo,
                                              const float* __restrict__ Wp,
                                              const float* __restrict__ Wn,
                                              const float* __restrict__ Wm,
                                              ushort* __restrict__ wout) {
    __shared__ int lhist[2 * NBUCK];
    __shared__ int lbase[2 * NBUCK];
    __shared__ ushort rows_s[PCHUNK];
    if (blockIdx.x >= PBLKS) {
        // -------- W pack path --------
        int idx = (blockIdx.x - PBLKS) * 256 + threadIdx.x;   // 0..98303
        const float* W;
        ushort* dst;
        int local;
        if (idx < 49152) {
            int m = idx >> 14;
            local = idx & 16383;
            W = (m == 0) ? Wo : (m == 1) ? Wp : Wn;
            dst = wout + m * 16384;
        } else {
            local = idx - 49152;
            W = Wm;
            dst = wout + 49152;
        }
        int j = local & 7, l = (local >> 3) & 63, t = (local >> 9) & 7, ks = local >> 12;
        int k = ks * 32 + (l >> 4) * 8 + j;
        int c = (l & 15) + 16 * t;
        dst[local] = f2bf(W[k * 128 + c]);
        return;
    }
    // -------- partition path --------
    long g0 = (long)blockIdx.x * PCHUNK;
    for (int i = threadIdx.x; i < 2 * NBUCK; i += 256) lhist[i] = 0;
    __syncthreads();
#pragma unroll
    for (int i = 0; i < 16; ++i) {
        long g = g0 + i * 256 + threadIdx.x;
        if (g < 2 * NEDGE) {
            int sign = g >= NEDGE;
            int e = (int)(g - (long)sign * NEDGE);
            int row = sign ? neg_idx[e] : pos_idx[e];
            rows_s[i * 256 + threadIdx.x] = (ushort)row;
            atomicAdd(&lhist[sign * NBUCK + (row >> 6)], 1);
        }
    }
    __syncthreads();
    for (int b = threadIdx.x; b < 2 * NBUCK; b += 256) {
        int c = lhist[b];
        lbase[b] = c ? atomicAdd(&ecnt[b], c) : 0;
        lhist[b] = 0;
    }
    __syncthreads();
#pragma unroll
    for (int i = 0; i < 16; ++i) {
        long g = g0 + i * 256 + threadIdx.x;
        if (g < 2 * NEDGE) {
            int sign = g >= NEDGE;
            int e = (int)(g - (long)sign * NEDGE);
            int row = rows_s[i * 256 + threadIdx.x];
            int col = sign ? neg_idx[NEDGE + e] : pos_idx[NEDGE + e];
            float wv = sign ? neg_w[e] : pos_w[e];
            int b = sign * NBUCK + (row >> 6);
            int off = lbase[b] + atomicAdd(&lhist[b], 1);
            if (off < ECAP)
                edges[(long)b * ECAP + off] =
                    make_int2((int)((uint)col | ((uint)(row & 63) << 16)), __float_as_int(wv));
        }
    }
}

// ---------------- bucket-local counting sort -> compressed CSR ----------------

__global__ __launch_bounds__(256) void bucket_csr_k(const int* __restrict__ ecnt,
                                                    const int2* __restrict__ edges,
                                                    uint* __restrict__ ecomp,
                                                    int2* __restrict__ rp2) {
    __shared__ int2 stage[ECAP];
    __shared__ int hist[64];
    __shared__ int base_[64];
    int b = blockIdx.x;
    int tid = threadIdx.x;
    int cnt = ecnt[b]; if (cnt > ECAP) cnt = ECAP;
    if (tid < 64) hist[tid] = 0;
    __syncthreads();
    long e0 = (long)b * ECAP;
    for (int i = tid; i < cnt; i += 256) {
        int2 e = edges[e0 + i];
        stage[i] = e;
        atomicAdd(&hist[((uint)e.x >> 16) & 63u], 1);
    }
    __syncthreads();
    if (tid < 64) {
        int v = hist[tid];
        int s = v;
#pragma unroll
        for (int off = 1; off < 64; off <<= 1) {
            int t = __shfl_up(s, off);
            if ((tid & 63) >= off) s += t;
        }
        int excl = s - v;
        base_[tid] = excl;
        int sign = b >= NBUCK;
        int r = (b - sign * NBUCK) * 64 + tid;
        rp2[sign * NNODES + r] = make_int2((int)(e0 + excl), (int)(e0 + excl + v));
        hist[tid] = 0;   // reuse as cursor
    }
    __syncthreads();
    for (int i = tid; i < cnt; i += 256) {
        int2 e = stage[i];
        int rl = ((uint)e.x >> 16) & 63u;
        int pos = base_[rl] + atomicAdd(&hist[rl], 1);
        ecomp[e0 + pos] = ((uint)e.x & 0xFFFFu) |
                          ((uint)f2bf(__int_as_float(e.y)) << 16);
    }
}

// ---------------- fused triple MFMA GEMM: x(f32) @ {W_org,W_pos,W_neg} ----------------
// outputs quarter-blocked bf16; fused per-channel stats for org.

__global__ __launch_bounds__(256) void mfma_gemm3_k(const float* __restrict__ x,
                                                    const ushort* __restrict__ B0,
                                                    const ushort* __restrict__ B1,
                                                    const ushort* __restrict__ B2,
                                                    ushort* __restrict__ O0,
                                                    ushort* __restrict__ O1,
                                                    ushort* __restrict__ O2,
                                                    float* __restrict__ sums,
                                                    float* __restrict__ sumsq) {
    __shared__ float cs[128], cq[128];
    int tid = threadIdx.x;
    int lane = tid & 63, wave = tid >> 6;
    if (tid < 128) { cs[tid] = 0.f; cq[tid] = 0.f; }
    __syncthreads();
    long rbase = (long)blockIdx.x * 64 + wave * 16;
    int r = lane & 15, kg = lane >> 4;
    const float* xr = x + (rbase + r) * 128 + kg * 8;
    bfrag a[4];
#pragma unroll
    for (int ks = 0; ks < 4; ++ks) {
        float4 lo = *(const float4*)(xr + ks * 32);
        float4 hi = *(const float4*)(xr + ks * 32 + 4);
        bfu t;
        t.u[0] = (uint)f2bf(lo.x) | ((uint)f2bf(lo.y) << 16);
        t.u[1] = (uint)f2bf(lo.z) | ((uint)f2bf(lo.w) << 16);
        t.u[2] = (uint)f2bf(hi.x) | ((uint)f2bf(hi.y) << 16);
        t.u[3] = (uint)f2bf(hi.z) | ((uint)f2bf(hi.w) << 16);
        a[ks] = t.v;
    }
    const ushort* Bs[3] = {B0, B1, B2};
    ushort* Os[3] = {O0, O1, O2};
    long orow = rbase + kg * 4;
#pragma unroll
    for (int m = 0; m < 3; ++m) {
        const bfrag* Bq = (const bfrag*)Bs[m] + lane;
        facc acc[8];
#pragma unroll
        for (int t = 0; t < 8; ++t) acc[t] = (facc){0.f, 0.f, 0.f, 0.f};
#pragma unroll
        for (int ks = 0; ks < 4; ++ks)
#pragma unroll
            for (int t = 0; t < 8; ++t)
                acc[t] = __builtin_amdgcn_mfma_f32_16x16x32_bf16(a[ks], Bq[(ks * 8 + t) * 64], acc[t], 0, 0, 0);
        ushort* O = Os[m];
#pragma unroll
        for (int t = 0; t < 8; ++t) {
            float s_ = 0.f, q_ = 0.f;
            // channel c = 16t + r -> blocked: q = t>>1, cc = (t&1)*16 + r
            long qb = (long)(t >> 1) * QSZ16 + (t & 1) * 16 + r;
#pragma unroll
            for (int j = 0; j < 4; ++j) {
                ushort bv = f2bf(acc[t][j]);
                O[qb + (orow + j) * 32] = bv;
                if (m == 0) {
                    float fv = bf2f(bv);
                    s_ += fv;
                    q_ = fmaf(fv, fv, q_);
                }
            }
            if (m == 0) {
                atomicAdd(&cs[16 * t + r], s_);
                atomicAdd(&cq[16 * t + r], q_);
            }
        }
    }
    __syncthreads();
    if (tid < 128) {
        atomicAdd(&sums[tid], cs[tid]);
        atomicAdd(&sumsq[tid], cq[tid]);
    }
}

// ---------------- quarter-blocked SpMM: split-row, 8 rows/wave x 2 half-groups ------
// grp = blockIdx.x & 7 pins each (sign,quarter) group to one XCD (2.56 MB table
// L2-resident). Wave = 8 rows; each row is walked by TWO 4-lane half-groups
// (lane bit 2 selects the half of the edge range), loop body identical to the
// proven unroll-2 uint4 form. Halves the serialized latency chain per row;
// one __shfl_xor(.,4) combines the halves; even half-groups store.

template<int PHASE>
__global__ __launch_bounds__(256) void spmmg_k(const int2* __restrict__ rp2,
                                               const uint* __restrict__ ec,
                                               const uint* __restrict__ p_in,
                                               const uint* __restrict__ n_in,
                                               const uint* __restrict__ p_prev,
                                               const uint* __restrict__ n_prev,
                                               uint* __restrict__ p_out,
                                               uint* __restrict__ n_out) {
    int grp = blockIdx.x & 7;
    int rg  = blockIdx.x >> 3;          // 0..1249
    int sign = grp >> 2, q = grp & 3;
    int tid = threadIdx.x;
    int w = tid >> 6, lane = tid & 63;
    int u = lane & 3;                   // uint4 index (8 bf16 channels)
    int half = (lane >> 2) & 1;         // which half of the row's edges
    int rl = lane >> 3;                 // row within wave (0..7)
    const uint4* in  = (const uint4*)((sign ? n_in : p_in) + q * QSZU);
    uint4* out = (uint4*)((sign ? n_out : p_out) + q * QSZU);
    int r = rg * 32 + w * 8 + rl;
    int2 se = rp2[sign * NNODES + r];
    int mid = (se.x + se.y) >> 1;
    int e  = half ? mid : se.x;
    int e1 = half ? se.y : mid;
    float a0 = 0.f, a1 = 0.f, a2 = 0.f, a3 = 0.f;
    float a4 = 0.f, a5 = 0.f, a6 = 0.f, a7 = 0.f;
    float b0 = 0.f, b1 = 0.f, b2 = 0.f, b3 = 0.f;
    float b4 = 0.f, b5 = 0.f, b6 = 0.f, b7 = 0.f;
    for (; e + 2 <= e1; e += 2) {
        uint ea = ec[e], eb = ec[e + 1];
        uint4 ga = in[(ea & 0xFFFFu) * 4 + u];
        uint4 gb = in[(eb & 0xFFFFu) * 4 + u];
        float wa = bhi(ea), wb = bhi(eb);
        a0 = fmaf(wa, blo(ga.x), a0); a1 = fmaf(wa, bhi(ga.x), a1);
        a2 = fmaf(wa, blo(ga.y), a2); a3 = fmaf(wa, bhi(ga.y), a3);
        a4 = fmaf(wa, blo(ga.z), a4); a5 = fmaf(wa, bhi(ga.z), a5);
        a6 = fmaf(wa, blo(ga.w), a6); a7 = fmaf(wa, bhi(ga.w), a7);
        b0 = fmaf(wb, blo(gb.x), b0); b1 = fmaf(wb, bhi(gb.x), b1);
        b2 = fmaf(wb, blo(gb.y), b2); b3 = fmaf(wb, bhi(gb.y), b3);
        b4 = fmaf(wb, blo(gb.z), b4); b5 = fmaf(wb, bhi(gb.z), b5);
        b6 = fmaf(wb, blo(gb.w), b6); b7 = fmaf(wb, bhi(gb.w), b7);
    }
    if (e < e1) {
        uint ea = ec[e];
        uint4 ga = in[(ea & 0xFFFFu) * 4 + u];
        float wa = bhi(ea);
        a0 = fmaf(wa, blo(ga.x), a0); a1 = fmaf(wa, bhi(ga.x), a1);
        a2 = fmaf(wa, blo(ga.y), a2); a3 = fmaf(wa, bhi(ga.y), a3);
        a4 = fmaf(wa, blo(ga.z), a4); a5 = fmaf(wa, bhi(ga.z), a5);
        a6 = fmaf(wa, blo(ga.w), a6); a7 = fmaf(wa, bhi(ga.w), a7);
    }
    a0 += b0; a1 += b1; a2 += b2; a3 += b3;
    a4 += b4; a5 += b5; a6 += b6; a7 += b7;
    // combine the two half-groups (lanes l and l^4 hold the two halves)
    a0 += __shfl_xor(a0, 4); a1 += __shfl_xor(a1, 4);
    a2 += __shfl_xor(a2, 4); a3 += __shfl_xor(a3, 4);
    a4 += __shfl_xor(a4, 4); a5 += __shfl_xor(a5, 4);
    a6 += __shfl_xor(a6, 4); a7 += __shfl_xor(a7, 4);
    if (half == 0) {
        uint4 res;
        if (PHASE == 1) {
            res.x = (uint)f2bf(2.f * a0) | ((uint)f2bf(2.f * a1) << 16);
            res.y = (uint)f2bf(2.f * a2) | ((uint)f2bf(2.f * a3) << 16);
            res.z = (uint)f2bf(2.f * a4) | ((uint)f2bf(2.f * a5) << 16);
            res.w = (uint)f2bf(2.f * a6) | ((uint)f2bf(2.f * a7) << 16);
        } else {
            const uint4* prev = (const uint4*)((sign ? n_prev : p_prev) + q * QSZU);
            uint4 pu = prev[r * 4 + u];
            float r0 = fmaf(1.875f, a0, -1.6875f * blo(pu.x));
            float r1 = fmaf(1.875f, a1, -1.6875f * bhi(pu.x));
            float r2 = fmaf(1.875f, a2, -1.6875f * blo(pu.y));
            float r3 = fmaf(1.875f, a3, -1.6875f * bhi(pu.y));
            float r4 = fmaf(1.875f, a4, -1.6875f * blo(pu.z));
            float r5 = fmaf(1.875f, a5, -1.6875f * bhi(pu.z));
            float r6 = fmaf(1.875f, a6, -1.6875f * blo(pu.w));
            float r7 = fmaf(1.875f, a7, -1.6875f * bhi(pu.w));
            res.x = (uint)f2bf(r0) | ((uint)f2bf(r1) << 16);
            res.y = (uint)f2bf(r2) | ((uint)f2bf(r3) << 16);
            res.z = (uint)f2bf(r4) | ((uint)f2bf(r5) << 16);
            res.w = (uint)f2bf(r6) | ((uint)f2bf(r7) << 16);
        }
        out[r * 4 + u] = res;
    }
}

// ---------------- batch stats for pos & neg (quarter-blocked bf16 input) ----------------

__global__ __launch_bounds__(256) void stats2_k(const ushort* __restrict__ pos,
                                                const ushort* __restrict__ neg,
                                                float* __restrict__ sums,
                                                float* __restrict__ sumsq) {
    int b = blockIdx.x;            // 626 blocks
    int sign = b >= 313;
    int blk = b - sign * 313;
    const ushort* buf = sign ? neg : pos;
    int c = threadIdx.x & 127, half = threadIdx.x >> 7;
    int qq = c >> 5, cc = c & 31;
    const ushort* base = buf + (long)qq * QSZ16 + cc;
    int r0 = blk * 128;
    int rend = r0 + 128; if (rend > NNODES) rend = NNODES;
    float s = 0.f, s2 = 0.f;
    for (int r = r0 + half; r < rend; r += 2) {
        float v = bf2f(base[r * 32]);
        s += v;
        s2 = fmaf(v, v, s2);
    }
    __shared__ float sh[256], sh2[256];
    sh[threadIdx.x] = s; sh2[threadIdx.x] = s2;
    __syncthreads();
    if (threadIdx.x < 128) {
        int sb = 128 + sign * 128;
        atomicAdd(&sums[sb + c],  sh[c]  + sh[c + 128]);
        atomicAdd(&sumsq[sb + c], sh2[c] + sh2[c + 128]);
    }
}

// ---------------- final MFMA GEMM K=384: BN-finalize + BN+PReLU+concat + row-norm ----

__global__ __launch_bounds__(256) void mfma_gemm_mlp_k(const ushort* __restrict__ org,
                                                       const ushort* __restrict__ pos,
                                                       const ushort* __restrict__ neg,
                                                       const float* __restrict__ sums,
                                                       const float* __restrict__ sumsq,
                                                       const float* __restrict__ g0,
                                                       const float* __restrict__ be0,
                                                       const float* __restrict__ g1,
                                                       const float* __restrict__ be1,
                                                       const float* __restrict__ g2,
                                                       const float* __restrict__ be2,
                                                       const float* __restrict__ prelu_w,
                                                       const ushort* __restrict__ Bp,
                                                       float* __restrict__ Out) {
    __shared__ __align__(16) float bnl[768];
    int tid = threadIdx.x;
    for (int i = tid; i < 384; i += 256) {
        int s = i >> 7, c = i & 127;
        float mean = sums[i] * (1.f / NNODES);
        float var  = sumsq[i] * (1.f / NNODES) - mean * mean;
        const float* g = (s == 0) ? g0 : (s == 1) ? g1 : g2;
        const float* b = (s == 0) ? be0 : (s == 1) ? be1 : be2;
        float sc = g[c] * rsqrtf(var + 1e-5f);
        bnl[s * 256 + c]       = sc;
        bnl[s * 256 + 128 + c] = b[c] - mean * sc;
    }
    __syncthreads();
    int lane = tid & 63, wave = tid >> 6;
    long rbase = (long)blockIdx.x * 64 + wave * 16;
    int r = lane & 15, kg = lane >> 4;
    float pw = prelu_w[0];
    facc acc[8];
#pragma unroll
    for (int t = 0; t < 8; ++t) acc[t] = (facc){0.f, 0.f, 0.f, 0.f};
    const bfrag* Bq = (const bfrag*)Bp + lane;
#pragma unroll
    for (int ks = 0; ks < 12; ++ks) {
        int c = ks * 32 + kg * 8;          // concat column of first elem
        int s = c >> 7;
        int off = c & 127;
        const ushort* src = (s == 0) ? org : (s == 1) ? pos : neg;
        const uint* srcu = (const uint*)src;
        uint4 u = *(const uint4*)(srcu + (long)(off >> 5) * QSZU + (rbase + r) * 16 + ((off & 31) >> 1));
        float4 sc_lo = *(const float4*)(bnl + s * 256 + off);
        float4 sc_hi = *(const float4*)(bnl + s * 256 + off + 4);
        float4 sh_lo = *(const float4*)(bnl + s * 256 + 128 + off);
        float4 sh_hi = *(const float4*)(bnl + s * 256 + 128 + off + 4);
        uint uu[4] = {u.x, u.y, u.z, u.w};
        float scv[8] = {sc_lo.x, sc_lo.y, sc_lo.z, sc_lo.w, sc_hi.x, sc_hi.y, sc_hi.z, sc_hi.w};
        float shv[8] = {sh_lo.x, sh_lo.y, sh_lo.z, sh_lo.w, sh_hi.x, sh_hi.y, sh_hi.z, sh_hi.w};
        bfu av;
#pragma unroll
        for (int k = 0; k < 4; ++k) {
            float vx = __uint_as_float(uu[k] << 16);
            float vy = __uint_as_float(uu[k] & 0xFFFF0000u);
            float ox = fmaf(vx, scv[2 * k],     shv[2 * k]);     ox = (ox >= 0.f) ? ox : pw * ox;
            float oy = fmaf(vy, scv[2 * k + 1], shv[2 * k + 1]); oy = (oy >= 0.f) ? oy : pw * oy;
            av.u[k] = (uint)f2bf(ox) | ((uint)f2bf(oy) << 16);
        }
#pragma unroll
        for (int t = 0; t < 8; ++t)
            acc[t] = __builtin_amdgcn_mfma_f32_16x16x32_bf16(av.v, Bq[(ks * 8 + t) * 64], acc[t], 0, 0, 0);
    }
    long orow = rbase + kg * 4;
#pragma unroll
    for (int j = 0; j < 4; ++j) {
        float ss = 0.f;
#pragma unroll
        for (int t = 0; t < 8; ++t) ss = fmaf(acc[t][j], acc[t][j], ss);
        ss += __shfl_xor(ss, 1);
        ss += __shfl_xor(ss, 2);
        ss += __shfl_xor(ss, 4);
        ss += __shfl_xor(ss, 8);
        float inv = 1.f / fmaxf(sqrtf(ss), 1e-12f);
#pragma unroll
        for (int t = 0; t < 8; ++t)
            Out[(orow + j) * 128 + 16 * t + r] = acc[t][j] * inv;
    }
}

// ---------------- launch ----------------

extern "C" void kernel_launch(void* const* d_in, const int* in_sizes, int n_in,
                              void* d_out, int out_size, void* d_ws, size_t ws_size,
                              hipStream_t stream) {
    const float* x       = (const float*)d_in[0];
    const int*   pos_idx = (const int*)d_in[1];
    const float* pos_w   = (const float*)d_in[2];
    const int*   neg_idx = (const int*)d_in[3];
    const float* neg_w   = (const float*)d_in[4];
    const float* W_org   = (const float*)d_in[5];
    const float* W_pos   = (const float*)d_in[6];
    const float* W_neg   = (const float*)d_in[7];
    const float* g_org   = (const float*)d_in[8];
    const float* b_org   = (const float*)d_in[9];
    const float* g_pos   = (const float*)d_in[10];
    const float* b_pos   = (const float*)d_in[11];
    const float* g_neg   = (const float*)d_in[12];
    const float* b_neg   = (const float*)d_in[13];
    const float* prelu_w = (const float*)d_in[14];
    const float* W_mlp   = (const float*)d_in[15];
    float* out = (float*)d_out;

    char* ws = (char*)d_ws;
    const size_t FB = (size_t)NNODES * 128 * 2;        // 10,240,000 B per feature buffer
    ushort* org0b = (ushort*)(ws);
    ushort* p0b   = (ushort*)(ws + FB);
    ushort* n0b   = (ushort*)(ws + 2 * FB);
    int2* edges   = (int2*)(ws + 3 * FB);              // staging, 14,080,000 B
    uint* ecomp   = (uint*)(ws + 3 * FB + 14080000);   // compressed, 7,040,000 B
    char* small   = ws + 3 * FB + 14080000 + 7040000;
    int* ecnt     = (int*)small;                       // 5000 -> pad 5120
    float* sums   = (float*)(small + 5120);            // 1536
    float* sumsq  = (float*)(small + 5120 + 1536);     // 1536 (memset 0..8192)
    int2* rp2     = (int2*)(small + 8192);             // 640,000
    ushort* Wb    = (ushort*)(small + 8192 + 640000);  // 196,608 B
    uint* t1_pos  = (uint*)d_out;                      // blocked bf16 scratch halves of d_out
    uint* t1_neg  = (uint*)d_out + 4 * QSZU;

    hipMemsetAsync(small, 0, 8192, stream);

    prep_k<<<PBLKS + 384, 256, 0, stream>>>(pos_idx, pos_w, neg_idx, neg_w, ecnt, edges,
                                            W_org, W_pos, W_neg, W_mlp, Wb);
    bucket_csr_k<<<2 * NBUCK, 256, 0, stream>>>(ecnt, edges, ecomp, rp2);

    mfma_gemm3_k<<<625, 256, 0, stream>>>(x, Wb, Wb + 16384, Wb + 32768,
                                          org0b, p0b, n0b, sums, sumsq);

    // Jacobi (a=b=1, K=3): x1 = 2*A@x0 ; x2 = 1.875*A@x1 - 1.6875*x0
    spmmg_k<1><<<10000, 256, 0, stream>>>(rp2, ecomp,
        (const uint*)p0b, (const uint*)n0b, nullptr, nullptr, t1_pos, t1_neg);
    spmmg_k<2><<<10000, 256, 0, stream>>>(rp2, ecomp,
        t1_pos, t1_neg, (const uint*)p0b, (const uint*)n0b, (uint*)p0b, (uint*)n0b);

    stats2_k<<<626, 256, 0, stream>>>(p0b, n0b, sums, sumsq);
    mfma_gemm_mlp_k<<<625, 256, 0, stream>>>(org0b, p0b, n0b, sums, sumsq,
                                             g_org, b_org, g_pos, b_pos, g_neg, b_neg,
                                             prelu_w, Wb + 49152, out);

    (void)in_sizes; (void)n_in; (void)out_size; (void)ws_size;
}